// Round 4
// baseline (131.177 us; speedup 1.0000x reference)
//
#include <hip/hip_runtime.h>

// ProfileHMM forward on MI355X — single fused kernel.
// Each block (256 threads) recomputes the HMM coefficient arrays in LDS
// (setup phase, ~us, barriers only here), then wave 0 runs the 255-step
// sequential scan: weighted prefix recurrence over 384 positions/lane-packed
// + scalar state I_384 carried per-lane (lane 63 authoritative).
// Emission loop split at sequence length n (mask is a contiguous prefix):
// loop1 always multiplies emissions (branch-free), loop2 skips them.

#define NEGC (-1.0e32f)

typedef float v2f __attribute__((ext_vector_type(2)));

#if __has_builtin(__builtin_elementwise_fma)
#define VFMA(a,b,c) __builtin_elementwise_fma((a),(b),(c))
#else
static __device__ __forceinline__ v2f VFMA(v2f a, v2f b, v2f c) {
    v2f r; r.x = fmaf(a.x,b.x,c.x); r.y = fmaf(a.y,b.y,c.y); return r;
}
#endif
#if __has_builtin(__builtin_elementwise_max)
#define VMAX(a,b) __builtin_elementwise_max((a),(b))
#else
static __device__ __forceinline__ v2f VMAX(v2f a, v2f b) {
    v2f r; r.x = fmaxf(a.x,b.x); r.y = fmaxf(a.y,b.y); return r;
}
#endif
static __device__ __forceinline__ v2f mkv2(float a, float b) { v2f r; r.x = a; r.y = b; return r; }

template<int CTRL>
__device__ __forceinline__ float fdpp(float x) {
    union { float f; int i; } u, r;
    u.f = x;
    r.i = __builtin_amdgcn_update_dpp(0, u.i, CTRL, 0xF, 0xF, true);
    return r.f;
}
// whole-wave shift right 1 (lane0 <- 0): row_shr:1 + row_bcast15 select
__device__ __forceinline__ float wshr1(float x, int lane) {
    float a = fdpp<0x111>(x);
    float b = fdpp<0x142>(x);
    return ((lane & 15) == 0) ? b : a;
}
__device__ __forceinline__ float rdlane63(float x) {
    union { float f; int i; } u; u.f = x;
    u.i = __builtin_amdgcn_readlane(u.i, 63);
    return u.f;
}

// LDS float layout (final): TAB [21 letters][64 lanes][12] = 16128, ES 16128..16152,
// lets bytes at float off 16152 (264 B). Setup scratch aliases 0..~10800 (pre-table).
#define L_TAB   0
#define L_ES    16128
#define L_LETS  16152
#define L_TOTAL 16224

#define S_RN    0
#define S_UN    2304
#define S_EWS   4608
#define S_ETMM  4993
#define S_ETII  5378
#define S_CS    5763
#define S_QA    6148
#define S_D2    6533
#define S_AEM   6917
#define S_AEI   7302
#define S_DMA   7687
#define S_DMB   8072
#define S_DIA   8457
#define S_DIB   8842
#define S_RAW   9227
#define S_RED   9998

struct Buf { v2f em0, em1, em2, ei0, ei1, ei2; float es; };

#define RENORM do { \
    v2f mv_ = VMAX(VMAX(Pm0,Pm1), VMAX(Pm2, VMAX(Pi0, VMAX(Pi1,Pi2)))); \
    float mxr_ = fmaxf(fmaxf(mv_.x, mv_.y), pi384); \
    mxr_ = fmaxf(mxr_, fdpp<0x111>(mxr_)); \
    mxr_ = fmaxf(mxr_, fdpp<0x112>(mxr_)); \
    mxr_ = fmaxf(mxr_, fdpp<0x114>(mxr_)); \
    mxr_ = fmaxf(mxr_, fdpp<0x118>(mxr_)); \
    mxr_ = fmaxf(mxr_, fdpp<0x142>(mxr_)); \
    mxr_ = fmaxf(mxr_, fdpp<0x143>(mxr_)); \
    float g_ = rdlane63(mxr_); \
    if (g_ > 0.f) { \
        float sc_ = 0x1p50f / g_; \
        logoff += logf(g_) - 34.65735902799726547f; \
        Pm0 *= sc_; Pm1 *= sc_; Pm2 *= sc_; Pi0 *= sc_; Pi1 *= sc_; Pi2 *= sc_; pi384 *= sc_; \
    } \
} while (0)

#define FILL(LM, E) do { \
    int lmv_ = (LM); \
    int lmc_ = lmv_ > 20 ? 20 : lmv_; \
    const float* bp_ = smem + lmc_*768 + lane12; \
    float4 q0_ = ((const float4*)bp_)[0], q1_ = ((const float4*)bp_)[1], q2_ = ((const float4*)bp_)[2]; \
    E.em0 = mkv2(q0_.x,q0_.y); E.em1 = mkv2(q0_.z,q0_.w); E.em2 = mkv2(q1_.x,q1_.y); \
    E.ei0 = mkv2(q1_.z,q1_.w); E.ei1 = mkv2(q2_.x,q2_.y); E.ei2 = mkv2(q2_.z,q2_.w); \
    E.es = smem[L_ES + lmv_]; \
} while (0)

#define CORE(CUR, EMIT, T) do { \
    float apx_ = wshr1(Pm2.y, lane); \
    float oldPm_ = Pm2.y; \
    v2f Ap0_ = mkv2(apx_, Pm0.x), Ap1_ = mkv2(Pm0.y, Pm1.x), Ap2_ = mkv2(Pm1.y, Pm2.x); \
    v2f E0_ = VFMA(Pi0, Cei0, Ap0_*Cem0); \
    v2f E1_ = VFMA(Pi1, Cei1, Ap1_*Cem1); \
    v2f E2_ = VFMA(Pi2, Cei2, Ap2_*Cem2); \
    float i0_ = E0_.x; \
    float i1_ = fmaf(w1, i0_, E0_.y); \
    float i2_ = fmaf(w2, i1_, E1_.x); \
    float i3_ = fmaf(w3, i2_, E1_.y); \
    float i4_ = fmaf(w4, i3_, E2_.x); \
    float i5_ = fmaf(w5, i4_, E2_.y); \
    float bb_; \
    if (fastAll) { bb_ = fmaf(Ar0, wshr1(i5_, lane), i5_); } \
    else { \
        bb_ = i5_; \
        bb_ = fmaf(Ar0, fdpp<0x111>(bb_), bb_); \
        bb_ = fmaf(Ar1, fdpp<0x112>(bb_), bb_); \
        bb_ = fmaf(Ar2, fdpp<0x114>(bb_), bb_); \
        bb_ = fmaf(Ar3, fdpp<0x118>(bb_), bb_); \
        bb_ = fmaf(A15, fdpp<0x142>(bb_), bb_); \
        bb_ = fmaf(A31, fdpp<0x143>(bb_), bb_); \
    } \
    float bx_ = wshr1(bb_, lane); \
    v2f Rv0_ = mkv2(bx_, fmaf(pw1, bx_, i0_)); \
    v2f Rv1_ = mkv2(fmaf(pw2, bx_, i1_), fmaf(pw3, bx_, i2_)); \
    v2f Rv2_ = mkv2(fmaf(pw4, bx_, i3_), fmaf(pw5, bx_, i4_)); \
    v2f nm0_ = VFMA(Cgm0, Rv0_, VFMA(Pi0, Cdmb0, Ap0_*Cdma0)); \
    v2f nm1_ = VFMA(Cgm1, Rv1_, VFMA(Pi1, Cdmb1, Ap1_*Cdma1)); \
    v2f nm2_ = VFMA(Cgm2, Rv2_, VFMA(Pi2, Cdmb2, Ap2_*Cdma2)); \
    v2f ni0_ = VFMA(Cgi0, Rv0_, VFMA(Pi0, Cdib0, Ap0_*Cdia0)); \
    v2f ni1_ = VFMA(Cgi1, Rv1_, VFMA(Pi1, Cdib1, Ap1_*Cdia1)); \
    v2f ni2_ = VFMA(Cgi2, Rv2_, VFMA(Pi2, Cdib2, Ap2_*Cdia2)); \
    float np_ = fmaf(oldPm_, sDia, fmaf(pi384, sDib, bb_)); /* sGi == 1 exactly */ \
    if (EMIT) { \
        nm0_ *= CUR.em0; nm1_ *= CUR.em1; nm2_ *= CUR.em2; \
        ni0_ *= CUR.ei0; ni1_ *= CUR.ei1; ni2_ *= CUR.ei2; \
        np_ *= CUR.es; \
    } \
    Pm0 = nm0_; Pm1 = nm1_; Pm2 = nm2_; Pi0 = ni0_; Pi1 = ni1_; Pi2 = ni2_; pi384 = np_; \
    if (((T) & 15) == 0) { RENORM; } \
} while (0)

__global__ __launch_bounds__(256, 1) void hmm_fused(
    const float* __restrict__ ps, const float* __restrict__ iseq,
    const float* __restrict__ rr, const float* __restrict__ uu,
    const float* __restrict__ seq, const float* __restrict__ lsc,
    float* __restrict__ out)
{
    __shared__ float smem[L_TOTAL];
    const int tid = threadIdx.x;
    const int lane = tid & 63;
    const int wvid = tid >> 6;
    const int b = blockIdx.x;
    unsigned char* lets = (unsigned char*)(smem + L_LETS);

    float* rn   = smem + S_RN;
    float* un   = smem + S_UN;
    float* ews  = smem + S_EWS;
    float* etmm = smem + S_ETMM;
    float* etii = smem + S_ETII;
    float* Cs   = smem + S_CS;
    float* qa   = smem + S_QA;
    float* d2s  = smem + S_D2;
    float* cAEM = smem + S_AEM;
    float* cAEI = smem + S_AEI;
    float* cDMA = smem + S_DMA;
    float* cDMB = smem + S_DMB;
    float* cDIA = smem + S_DIA;
    float* cDIB = smem + S_DIB;
    float* rawv = smem + S_RAW;
    float* red  = smem + S_RED;

    // ---- phase A: letters + row log-softmax of r,u ----
    {
        const float* p = seq + (size_t)b*5376 + tid*21;
        float s = 0.f, wsum = 0.f;
        #pragma unroll
        for (int a = 0; a < 21; ++a) { float v = p[a]; s += v; wsum += v*(float)a; }
        lets[tid] = (s > 0.5f) ? (unsigned char)(int)(wsum + 0.5f) : (unsigned char)21;
        if (tid < 8) lets[256 + tid] = (unsigned char)21;
    }
    for (int row = tid; row < 1152; row += 256) {
        float a = rr[row*2], c = rr[row*2+1];
        float mx = fmaxf(a, c);
        float l = mx + logf(expf(a-mx) + expf(c-mx));
        rn[row*2] = a - l; rn[row*2+1] = c - l;
        a = uu[row*2]; c = uu[row*2+1];
        mx = fmaxf(a, c);
        l = mx + logf(expf(a-mx) + expf(c-mx));
        un[row*2] = a - l; un[row*2+1] = c - l;
    }
    __syncthreads();
    for (int m = tid; m < 384; m += 256) {
        float d = rn[(m*3+2)*2+0] + un[(m*3+2)*2+1];
        d2s[m] = d;
        ews[m] = expf(d);
        etmm[m] = expf(rn[(m*3+2)*2+0] + un[(m*3+2)*2+0]);
        etii[m] = expf(rn[(m*3+2)*2+1]);
    }
    if (tid == 0) { ews[384] = 0.f; etmm[384] = 0.f; etii[384] = 1.f; }
    __syncthreads();
    // ---- scans: wave0 -> Cs (additive), wave1 -> qa (weighted reverse) ----
    if (tid < 64) {
        float incl[6]; float z = 0.f;
        #pragma unroll
        for (int i = 0; i < 6; ++i) { z += d2s[lane*6+i]; incl[i] = z; }
        float tot = z;
        #pragma unroll
        for (int d = 1; d < 64; d <<= 1) { float q = __shfl_up(tot, d); if (lane >= d) tot += q; }
        float excl = __shfl_up(tot, 1); if (lane == 0) excl = 0.f;
        #pragma unroll
        for (int i = 0; i < 6; ++i) Cs[lane*6+i+1] = excl + incl[i];
        if (lane == 0) Cs[0] = 0.f;
    } else if (tid < 128) {
        float wv6[6], xv[6], incl[6];
        #pragma unroll
        for (int i = 0; i < 6; ++i) {
            int s = 384 - (lane*6 + i);
            wv6[i] = ews[s]; xv[i] = etii[s] + etmm[s];
        }
        float z = 0.f, Wl = 1.f;
        #pragma unroll
        for (int i = 0; i < 6; ++i) { z = fmaf(wv6[i], z, xv[i]); incl[i] = z; Wl *= wv6[i]; }
        float val = z, wt = Wl;
        #pragma unroll
        for (int d = 1; d < 64; d <<= 1) {
            float pv = __shfl_up(val, d); float pwv = __shfl_up(wt, d);
            if (lane >= d) { val = fmaf(wt, pv, val); wt *= pwv; }
        }
        float excl = __shfl_up(val, 1); if (lane == 0) excl = 0.f;
        float pp = 1.f;
        #pragma unroll
        for (int i = 0; i < 6; ++i) {
            pp *= wv6[i];
            qa[383 - (lane*6 + i)] = fmaf(excl, pp, incl[i]);
        }
        if (lane == 0) qa[384] = 0.f;
    }
    __syncthreads();
    // ---- per-source coefficients + raw initial vector ----
    for (int k = tid; k < 769; k += 256) {
        int g = (k < 384) ? 0 : 1;
        int m = (k < 384) ? k : (k - 384);
        int s = m + 1 - g;
        float ss, sd, smv, si;
        if (s <= 383) {
            int base = (s*3 + g)*2;
            ss = rn[base+0]; si = rn[base+1];
            smv = un[base+0]; sd = un[base+1];
        } else { ss = NEGC; si = 0.f; smv = 0.f; sd = NEGC; }
        float d0 = (s <= 383) ? (ss + smv) : NEGC;
        float d1 = si;
        float q = qa[s];
        float lq = (q > 0.f) ? logf(q) : -1.0e30f;
        float ch = ss + sd + lq;
        float mx = fmaxf(fmaxf(d0, d1), ch);
        float Z = mx + logf(expf(d0-mx) + expf(d1-mx) + expf(ch-mx));
        float we = expf(ss + sd - Z);
        float w0 = expf(d0 - Z);
        float w1v = expf(d1 - Z);
        if (g == 0) { cAEM[s] = we; cDMA[s] = w0; cDIA[s] = w1v; }
        else        { cAEI[s] = we; cDMB[s] = w0; cDIB[s] = w1v; }
    }
    if (tid == 0) { cAEM[0] = 0.f; cDMA[0] = 0.f; cDIA[0] = 0.f; }
    {
        float r000 = rn[0], r001 = rn[1];
        float u000 = un[0], u001 = un[1];
        for (int k = tid; k < 769; k += 256) {
            int g = (k < 384) ? 0 : 1;
            int m = (k < 384) ? k : (k - 384);
            float v;
            if (m == 0) v = g ? r001 : (r000 + u000);
            else {
                float tt = g ? ((m <= 383) ? rn[(m*3+2)*2+1] : 0.f)
                             : (rn[(m*3+2)*2+0] + un[(m*3+2)*2+0]);
                v = r000 + u001 - Cs[1] + Cs[m] + tt;
            }
            rawv[k] = v;
        }
    }
    __syncthreads();
    // ---- block logsumexp of rawv; p0 in place ----
    {
        float lmax = -3.0e38f;
        for (int k = tid; k < 769; k += 256) lmax = fmaxf(lmax, rawv[k]);
        #pragma unroll
        for (int d = 1; d < 64; d <<= 1) lmax = fmaxf(lmax, __shfl_xor(lmax, d));
        if (lane == 0) red[wvid] = lmax;
    }
    __syncthreads();
    {
        float gmax = fmaxf(fmaxf(red[0], red[1]), fmaxf(red[2], red[3]));
        float lsum = 0.f;
        for (int k = tid; k < 769; k += 256) lsum += expf(rawv[k] - gmax);
        #pragma unroll
        for (int d = 1; d < 64; d <<= 1) lsum += __shfl_xor(lsum, d);
        if (lane == 0) red[4 + wvid] = lsum;
        __syncthreads();
        float lse = gmax + logf(red[4] + red[5] + red[6] + red[7]);
        for (int k = tid; k < 769; k += 256) rawv[k] = expf(rawv[k] - lse);
    }
    __syncthreads();
    // ---- all threads load per-lane regs (only wave0's survive) ----
    const int j0 = lane*6;
    const int lane12 = lane*12;
    v2f Cem0=mkv2(cAEM[j0],cAEM[j0+1]), Cem1=mkv2(cAEM[j0+2],cAEM[j0+3]), Cem2=mkv2(cAEM[j0+4],cAEM[j0+5]);
    v2f Cei0=mkv2(cAEI[j0],cAEI[j0+1]), Cei1=mkv2(cAEI[j0+2],cAEI[j0+3]), Cei2=mkv2(cAEI[j0+4],cAEI[j0+5]);
    v2f Cdma0=mkv2(cDMA[j0],cDMA[j0+1]), Cdma1=mkv2(cDMA[j0+2],cDMA[j0+3]), Cdma2=mkv2(cDMA[j0+4],cDMA[j0+5]);
    v2f Cdmb0=mkv2(cDMB[j0],cDMB[j0+1]), Cdmb1=mkv2(cDMB[j0+2],cDMB[j0+3]), Cdmb2=mkv2(cDMB[j0+4],cDMB[j0+5]);
    v2f Cdia0=mkv2(cDIA[j0],cDIA[j0+1]), Cdia1=mkv2(cDIA[j0+2],cDIA[j0+3]), Cdia2=mkv2(cDIA[j0+4],cDIA[j0+5]);
    v2f Cdib0=mkv2(cDIB[j0],cDIB[j0+1]), Cdib1=mkv2(cDIB[j0+2],cDIB[j0+3]), Cdib2=mkv2(cDIB[j0+4],cDIB[j0+5]);
    v2f Cgm0=mkv2(etmm[j0],etmm[j0+1]), Cgm1=mkv2(etmm[j0+2],etmm[j0+3]), Cgm2=mkv2(etmm[j0+4],etmm[j0+5]);
    v2f Cgi0=mkv2(etii[j0],etii[j0+1]), Cgi1=mkv2(etii[j0+2],etii[j0+3]), Cgi2=mkv2(etii[j0+4],etii[j0+5]);
    v2f Pm0=mkv2(rawv[j0],rawv[j0+1]), Pm1=mkv2(rawv[j0+2],rawv[j0+3]), Pm2=mkv2(rawv[j0+4],rawv[j0+5]);
    v2f Pi0=mkv2(rawv[384+j0],rawv[384+j0+1]), Pi1=mkv2(rawv[384+j0+2],rawv[384+j0+3]), Pi2=mkv2(rawv[384+j0+4],rawv[384+j0+5]);
    float pi384 = rawv[768];
    const float sDia = cDIA[384], sDib = cDIB[384];
    const float W0=ews[j0], w1=ews[j0+1], w2=ews[j0+2], w3=ews[j0+3], w4=ews[j0+4], w5=ews[j0+5];
    __syncthreads();
    // ---- emission table build (overwrites scratch) ----
    for (int row = tid; row < 769; row += 256) {
        const float* src = (row < 384) ? (ps + row*21) : (iseq + (row-384)*21);
        float mx = -3.0e38f;
        for (int a = 0; a < 21; ++a) mx = fmaxf(mx, src[a]);
        float sm2 = 0.f;
        for (int a = 0; a < 21; ++a) sm2 += expf(src[a]-mx);
        float inv = 1.0f / sm2;
        if (row < 768) {
            int j = (row < 384) ? row : (row - 384);
            int slot = (j/6)*12 + ((row < 384) ? 0 : 6) + (j%6);
            float* dst = smem + L_TAB + slot;
            for (int a = 0; a < 21; ++a) dst[a*768] = expf(src[a]-mx)*inv;
        } else {
            for (int a = 0; a < 21; ++a) smem[L_ES + a] = expf(src[a]-mx)*inv;
            smem[L_ES + 21] = 1.0f; smem[L_ES + 22] = 1.0f; smem[L_ES + 23] = 1.0f;
        }
    }
    __syncthreads();
    if (wvid != 0) return;

    // ================= wave 0: the sequential scan =================
    // sequence length n (mask is a contiguous prefix)
    int n = 0;
    #pragma unroll
    for (int c = 0; c < 4; ++c)
        n += __popcll(__ballot(lets[c*64 + lane] != (unsigned char)21));

    const float pw1 = W0, pw2 = pw1*w1, pw3 = pw2*w2, pw4 = pw3*w3, pw5 = pw4*w4;
    const float W = pw5*w5;
    float p_ = W;
    const float Ar0 = p_;
    { float q = __shfl_up(p_, 1); p_ *= q; } const float Ar1 = p_;
    { float q = __shfl_up(p_, 2); p_ *= q; } const float Ar2 = p_;
    { float q = __shfl_up(p_, 4); p_ *= q; } const float Ar3 = p_;
    float prefR = W;
    #pragma unroll
    for (int d = 1; d < 16; d <<= 1) { float q = __shfl_up(prefR, d); if ((lane & 15) >= d) prefR *= q; }
    const int rw = lane >> 4;
    const float A15 = (rw == 1 || rw == 3) ? prefR : 0.f;
    const float s47 = __shfl(prefR, 47);
    const float A31 = (rw == 2) ? prefR : ((rw == 3) ? prefR * s47 : 0.f);
    bool bad = (Ar1 != 0.f) || (Ar2 != 0.f) || (Ar3 != 0.f)
             || ((A15 != 0.f) && ((lane & 15) >= 1))
             || ((A31 != 0.f) && (lane >= 33));
    const bool fastAll = (__ballot(bad) == 0ull);

    float logoff = 0.f;
    {   // t = 0 emission + renorm to 2^50
        int lm0 = (int)lets[0];
        if (lm0 != 21) {
            const float* bp = smem + lm0*768 + lane12;
            float4 q0 = ((const float4*)bp)[0], q1 = ((const float4*)bp)[1], q2 = ((const float4*)bp)[2];
            Pm0 *= mkv2(q0.x,q0.y); Pm1 *= mkv2(q0.z,q0.w); Pm2 *= mkv2(q1.x,q1.y);
            Pi0 *= mkv2(q1.z,q1.w); Pi1 *= mkv2(q2.x,q2.y); Pi2 *= mkv2(q2.z,q2.w);
            pi384 *= smem[L_ES + lm0];
        }
        RENORM;
    }

    Buf bA, bB;
    FILL((int)lets[1], bA);
    FILL((int)lets[2], bB);
    int t = 1;
    for (; t + 1 < n; t += 2) {
        { Buf cur = bA; FILL((int)lets[t+2], bA); CORE(cur, 1, t); }
        { Buf cur = bB; FILL((int)lets[t+3], bB); CORE(cur, 1, t+1); }
    }
    if (t < n) { Buf cur = bA; CORE(cur, 1, t); ++t; }
    for (; t + 1 < 256; t += 2) { CORE(bA, 0, t); CORE(bA, 0, t+1); }
    if (t < 256) { CORE(bA, 0, t); }

    v2f sv = Pm0 + Pm1 + Pm2 + Pi0 + Pi1 + Pi2;
    float s = sv.x + sv.y + ((lane == 63) ? pi384 : 0.f);
    s += fdpp<0x111>(s); s += fdpp<0x112>(s); s += fdpp<0x114>(s); s += fdpp<0x118>(s);
    s += fdpp<0x142>(s); s += fdpp<0x143>(s);
    if (lane == 63) out[b] = lsc[0] * (logf(s) + logoff);
}

extern "C" void kernel_launch(void* const* d_in, const int* in_sizes, int n_in,
                              void* d_out, int out_size, void* d_ws, size_t ws_size,
                              hipStream_t stream)
{
    const float* ps   = (const float*)d_in[0];  // precursor_seq (384,21)
    const float* iseq = (const float*)d_in[1];  // insert_seq (385,21)
    const float* ins  = (const float*)d_in[2];  // insert (384,3,2)
    const float* del  = (const float*)d_in[3];  // delete (384,3,2)
    const float* seq  = (const float*)d_in[4];  // seq_data (64,256,21)
    const float* lsc  = (const float*)d_in[5];  // local_scale (1,)
    float* out = (float*)d_out;
    hmm_fused<<<64, 256, 0, stream>>>(ps, iseq, ins, del, seq, lsc, out);
}

// Round 5
// 108.833 us; speedup vs baseline: 1.2053x; 1.2053x over previous
//
#include <hip/hip_runtime.h>

// ProfileHMM forward on MI355X — single fused kernel.
// Each block (256 threads) builds HMM coefficients in LDS, then wave 0 runs
// the sequential scan (weighted prefix recurrence over 384 positions + scalar
// state I_384). Key facts: normalized T has unit row sums and missing steps
// have unit emissions => steps t>=n are exact no-ops for the final logsumexp
// (early exit). Rotating 3-buffer emission pipeline, DPP wave_shr:1 cross-lane,
// renorm every 6 steps to 2^60 (keeps all states in normal fp32 range).

#define NEGC (-1.0e32f)

typedef float v2f __attribute__((ext_vector_type(2)));

#if __has_builtin(__builtin_elementwise_fma)
#define VFMA(a,b,c) __builtin_elementwise_fma((a),(b),(c))
#else
static __device__ __forceinline__ v2f VFMA(v2f a, v2f b, v2f c) {
    v2f r; r.x = fmaf(a.x,b.x,c.x); r.y = fmaf(a.y,b.y,c.y); return r;
}
#endif
#if __has_builtin(__builtin_elementwise_max)
#define VMAX(a,b) __builtin_elementwise_max((a),(b))
#else
static __device__ __forceinline__ v2f VMAX(v2f a, v2f b) {
    v2f r; r.x = fmaxf(a.x,b.x); r.y = fmaxf(a.y,b.y); return r;
}
#endif
static __device__ __forceinline__ v2f mkv2(float a, float b) { v2f r; r.x = a; r.y = b; return r; }

template<int CTRL>
__device__ __forceinline__ float fdpp(float x) {
    union { float f; int i; } u, r;
    u.f = x;
    r.i = __builtin_amdgcn_update_dpp(0, u.i, CTRL, 0xF, 0xF, true);
    return r.f;
}
// whole-wave shift right by 1 lane, lane0 <- 0 (gfx9 DPP wave_shr:1)
__device__ __forceinline__ float wsr1(float x) { return fdpp<0x138>(x); }
__device__ __forceinline__ float rdlane63(float x) {
    union { float f; int i; } u; u.f = x;
    u.i = __builtin_amdgcn_readlane(u.i, 63);
    return u.f;
}

// LDS float layout (scan phase): TAB [21][64][12]=16128, ES 16128..16152,
// lets bytes at float-offset 16152 (264 B). Setup scratch aliases 0..~10010.
#define L_TAB   0
#define L_ES    16128
#define L_LETS  16152
#define L_TOTAL 16224

#define S_RN    0
#define S_UN    2304
#define S_EWS   4608
#define S_ETMM  4993
#define S_ETII  5378
#define S_CS    5763
#define S_QA    6148
#define S_D2    6533
#define S_AEM   6917
#define S_AEI   7302
#define S_DMA   7687
#define S_DMB   8072
#define S_DIA   8457
#define S_DIB   8842
#define S_RAW   9227
#define S_RED   9998

struct Buf { v2f em0, em1, em2, ei0, ei1, ei2; float es; };

#define RENORM do { \
    v2f mv_ = VMAX(VMAX(Pm0,Pm1), VMAX(Pm2, VMAX(Pi0, VMAX(Pi1,Pi2)))); \
    float mxr_ = fmaxf(fmaxf(mv_.x, mv_.y), pi384); \
    mxr_ = fmaxf(mxr_, fdpp<0x111>(mxr_)); \
    mxr_ = fmaxf(mxr_, fdpp<0x112>(mxr_)); \
    mxr_ = fmaxf(mxr_, fdpp<0x114>(mxr_)); \
    mxr_ = fmaxf(mxr_, fdpp<0x118>(mxr_)); \
    mxr_ = fmaxf(mxr_, fdpp<0x142>(mxr_)); \
    mxr_ = fmaxf(mxr_, fdpp<0x143>(mxr_)); \
    float g_ = rdlane63(mxr_); \
    if (g_ > 0.f) { \
        float sc_ = 0x1p60f / g_; \
        logoff += __logf(g_) - 41.588830833596718565f; \
        Pm0 *= sc_; Pm1 *= sc_; Pm2 *= sc_; Pi0 *= sc_; Pi1 *= sc_; Pi2 *= sc_; pi384 *= sc_; \
    } \
} while (0)

#define FILL(LM, E) do { \
    int lmv_ = (LM); \
    int lmc_ = lmv_ > 20 ? 20 : lmv_; \
    const float* bp_ = smem + lmc_*768 + lane12; \
    float4 q0_ = ((const float4*)bp_)[0], q1_ = ((const float4*)bp_)[1], q2_ = ((const float4*)bp_)[2]; \
    E.em0 = mkv2(q0_.x,q0_.y); E.em1 = mkv2(q0_.z,q0_.w); E.em2 = mkv2(q1_.x,q1_.y); \
    E.ei0 = mkv2(q1_.z,q1_.w); E.ei1 = mkv2(q2_.x,q2_.y); E.ei2 = mkv2(q2_.z,q2_.w); \
    E.es = smem[L_ES + lmv_]; \
} while (0)

#define CORE(CUR, FAST) do { \
    float apx_ = wsr1(Pm2.y); \
    float oldPm_ = Pm2.y; \
    v2f Ap0_ = mkv2(apx_, Pm0.x), Ap1_ = mkv2(Pm0.y, Pm1.x), Ap2_ = mkv2(Pm1.y, Pm2.x); \
    v2f E0_ = VFMA(Pi0, Cei0, Ap0_*Cem0); \
    v2f E1_ = VFMA(Pi1, Cei1, Ap1_*Cem1); \
    v2f E2_ = VFMA(Pi2, Cei2, Ap2_*Cem2); \
    float i0_ = E0_.x; \
    float i1_ = fmaf(w1, i0_, E0_.y); \
    float i2_ = fmaf(w2, i1_, E1_.x); \
    float i3_ = fmaf(w3, i2_, E1_.y); \
    float i4_ = fmaf(w4, i3_, E2_.x); \
    float i5_ = fmaf(w5, i4_, E2_.y); \
    float bb_; \
    if (FAST) { bb_ = fmaf(Ar0, wsr1(i5_), i5_); } \
    else { \
        bb_ = i5_; \
        bb_ = fmaf(Ar0, fdpp<0x111>(bb_), bb_); \
        bb_ = fmaf(Ar1, fdpp<0x112>(bb_), bb_); \
        bb_ = fmaf(Ar2, fdpp<0x114>(bb_), bb_); \
        bb_ = fmaf(Ar3, fdpp<0x118>(bb_), bb_); \
        bb_ = fmaf(A15, fdpp<0x142>(bb_), bb_); \
        bb_ = fmaf(A31, fdpp<0x143>(bb_), bb_); \
    } \
    float bx_ = wsr1(bb_); \
    v2f Rv0_ = mkv2(bx_, fmaf(pw1, bx_, i0_)); \
    v2f Rv1_ = mkv2(fmaf(pw2, bx_, i1_), fmaf(pw3, bx_, i2_)); \
    v2f Rv2_ = mkv2(fmaf(pw4, bx_, i3_), fmaf(pw5, bx_, i4_)); \
    v2f nm0_ = VFMA(Cgm0, Rv0_, VFMA(Pi0, Cdmb0, Ap0_*Cdma0)); \
    v2f nm1_ = VFMA(Cgm1, Rv1_, VFMA(Pi1, Cdmb1, Ap1_*Cdma1)); \
    v2f nm2_ = VFMA(Cgm2, Rv2_, VFMA(Pi2, Cdmb2, Ap2_*Cdma2)); \
    v2f ni0_ = VFMA(Cgi0, Rv0_, VFMA(Pi0, Cdib0, Ap0_*Cdia0)); \
    v2f ni1_ = VFMA(Cgi1, Rv1_, VFMA(Pi1, Cdib1, Ap1_*Cdia1)); \
    v2f ni2_ = VFMA(Cgi2, Rv2_, VFMA(Pi2, Cdib2, Ap2_*Cdia2)); \
    float np_ = ((oldPm_ + pi384) + bb_) * CUR.es; /* cDIA[384]==cDIB[384]==1 exactly */ \
    Pm0 = nm0_*CUR.em0; Pm1 = nm1_*CUR.em1; Pm2 = nm2_*CUR.em2; \
    Pi0 = ni0_*CUR.ei0; Pi1 = ni1_*CUR.ei1; Pi2 = ni2_*CUR.ei2; \
    pi384 = np_; \
} while (0)

// FILL buf BC (emissions for step T+2) from letter reg LA; reload LA with
// letter for step T+5's FILL; run CORE on buf BA (step T). Rotation period 3.
#define ITER(BA,BB,BC,LA,LB,LC,TIDX,FAST) do { \
    FILL(LA, BC); \
    LA = (int)lets[(TIDX)+5]; \
    CORE(BA, FAST); \
} while (0)

#define SCANLOOP(FAST) do { \
    for (int it = 0; it < bodies; ++it, t += 6) { \
        ITER(bA,bB,bC,lA,lB,lC,t,FAST); \
        ITER(bB,bC,bA,lB,lC,lA,t+1,FAST); \
        ITER(bC,bA,bB,lC,lA,lB,t+2,FAST); \
        ITER(bA,bB,bC,lA,lB,lC,t+3,FAST); \
        ITER(bB,bC,bA,lB,lC,lA,t+4,FAST); \
        ITER(bC,bA,bB,lC,lA,lB,t+5,FAST); \
        RENORM; \
    } \
    if (rem > 0) { ITER(bA,bB,bC,lA,lB,lC,t,FAST); ++t; } \
    if (rem > 1) { ITER(bB,bC,bA,lB,lC,lA,t,FAST); ++t; } \
    if (rem > 2) { ITER(bC,bA,bB,lC,lA,lB,t,FAST); ++t; } \
    if (rem > 3) { ITER(bA,bB,bC,lA,lB,lC,t,FAST); ++t; } \
    if (rem > 4) { ITER(bB,bC,bA,lB,lC,lA,t,FAST); ++t; } \
} while (0)

__global__ __launch_bounds__(256, 1) void hmm_fused(
    const float* __restrict__ ps, const float* __restrict__ iseq,
    const float* __restrict__ rr, const float* __restrict__ uu,
    const float* __restrict__ seq, const float* __restrict__ lsc,
    float* __restrict__ out)
{
    __shared__ float smem[L_TOTAL];
    const int tid = threadIdx.x;
    const int lane = tid & 63;
    const int wvid = tid >> 6;
    const int b = blockIdx.x;
    unsigned char* lets = (unsigned char*)(smem + L_LETS);

    float* rn   = smem + S_RN;
    float* un   = smem + S_UN;
    float* ews  = smem + S_EWS;
    float* etmm = smem + S_ETMM;
    float* etii = smem + S_ETII;
    float* Cs   = smem + S_CS;
    float* qa   = smem + S_QA;
    float* d2s  = smem + S_D2;
    float* cAEM = smem + S_AEM;
    float* cAEI = smem + S_AEI;
    float* cDMA = smem + S_DMA;
    float* cDMB = smem + S_DMB;
    float* cDIA = smem + S_DIA;
    float* cDIB = smem + S_DIB;
    float* rawv = smem + S_RAW;
    float* red  = smem + S_RED;

    // ---- letters + row log-softmax of r,u ----
    {
        const float* p = seq + (size_t)b*5376 + tid*21;
        float s = 0.f, wsum = 0.f;
        #pragma unroll
        for (int a = 0; a < 21; ++a) { float v = p[a]; s += v; wsum += v*(float)a; }
        lets[tid] = (s > 0.5f) ? (unsigned char)(int)(wsum + 0.5f) : (unsigned char)21;
        if (tid < 8) lets[256 + tid] = (unsigned char)21;
    }
    for (int row = tid; row < 1152; row += 256) {
        float a = rr[row*2], c = rr[row*2+1];
        float mx = fmaxf(a, c);
        float l = mx + __logf(__expf(a-mx) + __expf(c-mx));
        rn[row*2] = a - l; rn[row*2+1] = c - l;
        a = uu[row*2]; c = uu[row*2+1];
        mx = fmaxf(a, c);
        l = mx + __logf(__expf(a-mx) + __expf(c-mx));
        un[row*2] = a - l; un[row*2+1] = c - l;
    }
    __syncthreads();
    for (int m = tid; m < 384; m += 256) {
        float d = rn[(m*3+2)*2+0] + un[(m*3+2)*2+1];
        d2s[m] = d;
        ews[m] = __expf(d);
        etmm[m] = __expf(rn[(m*3+2)*2+0] + un[(m*3+2)*2+0]);
        etii[m] = __expf(rn[(m*3+2)*2+1]);
    }
    if (tid == 0) { ews[384] = 0.f; etmm[384] = 0.f; etii[384] = 1.f; }
    __syncthreads();
    // ---- wave0: Cs additive scan; wave1: qa weighted reverse scan ----
    if (tid < 64) {
        float incl[6]; float z = 0.f;
        #pragma unroll
        for (int i = 0; i < 6; ++i) { z += d2s[lane*6+i]; incl[i] = z; }
        float tot = z;
        #pragma unroll
        for (int d = 1; d < 64; d <<= 1) { float q = __shfl_up(tot, d); if (lane >= d) tot += q; }
        float excl = __shfl_up(tot, 1); if (lane == 0) excl = 0.f;
        #pragma unroll
        for (int i = 0; i < 6; ++i) Cs[lane*6+i+1] = excl + incl[i];
        if (lane == 0) Cs[0] = 0.f;
    } else if (tid < 128) {
        float wv6[6], xv[6], incl[6];
        #pragma unroll
        for (int i = 0; i < 6; ++i) {
            int s = 384 - (lane*6 + i);
            wv6[i] = ews[s]; xv[i] = etii[s] + etmm[s];
        }
        float z = 0.f, Wl = 1.f;
        #pragma unroll
        for (int i = 0; i < 6; ++i) { z = fmaf(wv6[i], z, xv[i]); incl[i] = z; Wl *= wv6[i]; }
        float val = z, wt = Wl;
        #pragma unroll
        for (int d = 1; d < 64; d <<= 1) {
            float pv = __shfl_up(val, d); float pwv = __shfl_up(wt, d);
            if (lane >= d) { val = fmaf(wt, pv, val); wt *= pwv; }
        }
        float excl = __shfl_up(val, 1); if (lane == 0) excl = 0.f;
        float pp = 1.f;
        #pragma unroll
        for (int i = 0; i < 6; ++i) {
            pp *= wv6[i];
            qa[383 - (lane*6 + i)] = fmaf(excl, pp, incl[i]);
        }
        if (lane == 0) qa[384] = 0.f;
    }
    __syncthreads();
    // ---- per-source coefficients + raw initial vector ----
    for (int k = tid; k < 769; k += 256) {
        int g = (k < 384) ? 0 : 1;
        int m = (k < 384) ? k : (k - 384);
        int s = m + 1 - g;
        float ss, sd, smv, si;
        if (s <= 383) {
            int base = (s*3 + g)*2;
            ss = rn[base+0]; si = rn[base+1];
            smv = un[base+0]; sd = un[base+1];
        } else { ss = NEGC; si = 0.f; smv = 0.f; sd = NEGC; }
        float d0 = (s <= 383) ? (ss + smv) : NEGC;
        float d1 = si;
        float q = qa[s];
        float lq = (q > 0.f) ? __logf(q) : -1.0e30f;
        float ch = ss + sd + lq;
        float mx = fmaxf(fmaxf(d0, d1), ch);
        float Z = mx + __logf(__expf(d0-mx) + __expf(d1-mx) + __expf(ch-mx));
        float we = __expf(ss + sd - Z);
        float w0 = __expf(d0 - Z);
        float w1v = __expf(d1 - Z);
        if (g == 0) { cAEM[s] = we; cDMA[s] = w0; cDIA[s] = w1v; }
        else        { cAEI[s] = we; cDMB[s] = w0; cDIB[s] = w1v; }
    }
    if (tid == 0) { cAEM[0] = 0.f; cDMA[0] = 0.f; cDIA[0] = 0.f; }
    {
        float r000 = rn[0], r001 = rn[1];
        float u000 = un[0], u001 = un[1];
        for (int k = tid; k < 769; k += 256) {
            int g = (k < 384) ? 0 : 1;
            int m = (k < 384) ? k : (k - 384);
            float v;
            if (m == 0) v = g ? r001 : (r000 + u000);
            else {
                float tt = g ? ((m <= 383) ? rn[(m*3+2)*2+1] : 0.f)
                             : (rn[(m*3+2)*2+0] + un[(m*3+2)*2+0]);
                v = r000 + u001 - Cs[1] + Cs[m] + tt;
            }
            rawv[k] = v;
        }
    }
    __syncthreads();
    // ---- block logsumexp of rawv; p0 in place ----
    {
        float lmax = -3.0e38f;
        for (int k = tid; k < 769; k += 256) lmax = fmaxf(lmax, rawv[k]);
        #pragma unroll
        for (int d = 1; d < 64; d <<= 1) lmax = fmaxf(lmax, __shfl_xor(lmax, d));
        if (lane == 0) red[wvid] = lmax;
    }
    __syncthreads();
    {
        float gmax = fmaxf(fmaxf(red[0], red[1]), fmaxf(red[2], red[3]));
        float lsum = 0.f;
        for (int k = tid; k < 769; k += 256) lsum += __expf(rawv[k] - gmax);
        #pragma unroll
        for (int d = 1; d < 64; d <<= 1) lsum += __shfl_xor(lsum, d);
        if (lane == 0) red[4 + wvid] = lsum;
        __syncthreads();
        float lse = gmax + __logf(red[4] + red[5] + red[6] + red[7]);
        for (int k = tid; k < 769; k += 256) rawv[k] = __expf(rawv[k] - lse);
    }
    __syncthreads();
    // ---- load per-lane regs (only wave0's survive) ----
    const int j0 = lane*6;
    const int lane12 = lane*12;
    v2f Cem0=mkv2(cAEM[j0],cAEM[j0+1]), Cem1=mkv2(cAEM[j0+2],cAEM[j0+3]), Cem2=mkv2(cAEM[j0+4],cAEM[j0+5]);
    v2f Cei0=mkv2(cAEI[j0],cAEI[j0+1]), Cei1=mkv2(cAEI[j0+2],cAEI[j0+3]), Cei2=mkv2(cAEI[j0+4],cAEI[j0+5]);
    v2f Cdma0=mkv2(cDMA[j0],cDMA[j0+1]), Cdma1=mkv2(cDMA[j0+2],cDMA[j0+3]), Cdma2=mkv2(cDMA[j0+4],cDMA[j0+5]);
    v2f Cdmb0=mkv2(cDMB[j0],cDMB[j0+1]), Cdmb1=mkv2(cDMB[j0+2],cDMB[j0+3]), Cdmb2=mkv2(cDMB[j0+4],cDMB[j0+5]);
    v2f Cdia0=mkv2(cDIA[j0],cDIA[j0+1]), Cdia1=mkv2(cDIA[j0+2],cDIA[j0+3]), Cdia2=mkv2(cDIA[j0+4],cDIA[j0+5]);
    v2f Cdib0=mkv2(cDIB[j0],cDIB[j0+1]), Cdib1=mkv2(cDIB[j0+2],cDIB[j0+3]), Cdib2=mkv2(cDIB[j0+4],cDIB[j0+5]);
    v2f Cgm0=mkv2(etmm[j0],etmm[j0+1]), Cgm1=mkv2(etmm[j0+2],etmm[j0+3]), Cgm2=mkv2(etmm[j0+4],etmm[j0+5]);
    v2f Cgi0=mkv2(etii[j0],etii[j0+1]), Cgi1=mkv2(etii[j0+2],etii[j0+3]), Cgi2=mkv2(etii[j0+4],etii[j0+5]);
    v2f Pm0=mkv2(rawv[j0],rawv[j0+1]), Pm1=mkv2(rawv[j0+2],rawv[j0+3]), Pm2=mkv2(rawv[j0+4],rawv[j0+5]);
    v2f Pi0=mkv2(rawv[384+j0],rawv[384+j0+1]), Pi1=mkv2(rawv[384+j0+2],rawv[384+j0+3]), Pi2=mkv2(rawv[384+j0+4],rawv[384+j0+5]);
    float pi384 = rawv[768];
    const float W0=ews[j0], w1=ews[j0+1], w2=ews[j0+2], w3=ews[j0+3], w4=ews[j0+4], w5=ews[j0+5];
    __syncthreads();
    // ---- emission table build (overwrites setup scratch) ----
    for (int row = tid; row < 769; row += 256) {
        const float* src = (row < 384) ? (ps + row*21) : (iseq + (row-384)*21);
        float mx = -3.0e38f;
        for (int a = 0; a < 21; ++a) mx = fmaxf(mx, src[a]);
        float sm2 = 0.f;
        for (int a = 0; a < 21; ++a) sm2 += __expf(src[a]-mx);
        float inv = 1.0f / sm2;
        if (row < 768) {
            int j = (row < 384) ? row : (row - 384);
            int slot = (j/6)*12 + ((row < 384) ? 0 : 6) + (j%6);
            float* dst = smem + L_TAB + slot;
            for (int a = 0; a < 21; ++a) dst[a*768] = __expf(src[a]-mx)*inv;
        } else {
            for (int a = 0; a < 21; ++a) smem[L_ES + a] = __expf(src[a]-mx)*inv;
            smem[L_ES + 21] = 1.0f; smem[L_ES + 22] = 1.0f; smem[L_ES + 23] = 1.0f;
        }
    }
    __syncthreads();
    if (wvid != 0) return;

    // ================= wave 0: the sequential scan =================
    int n = 0;
    #pragma unroll
    for (int c = 0; c < 4; ++c)
        n += __popcll(__ballot(lets[c*64 + lane] != (unsigned char)21));

    const float pw1 = W0, pw2 = pw1*w1, pw3 = pw2*w2, pw4 = pw3*w3, pw5 = pw4*w4;
    const float W = pw5*w5;
    float p_ = W;
    const float Ar0 = p_;
    { float q = __shfl_up(p_, 1); p_ *= q; } const float Ar1 = p_;
    { float q = __shfl_up(p_, 2); p_ *= q; } const float Ar2 = p_;
    { float q = __shfl_up(p_, 4); p_ *= q; } const float Ar3 = p_;
    float prefR = W;
    #pragma unroll
    for (int d = 1; d < 16; d <<= 1) { float q = __shfl_up(prefR, d); if ((lane & 15) >= d) prefR *= q; }
    const int rw = lane >> 4;
    const float A15 = (rw == 1 || rw == 3) ? prefR : 0.f;
    const float s47 = __shfl(prefR, 47);
    const float A31 = (rw == 2) ? prefR : ((rw == 3) ? prefR * s47 : 0.f);
    bool bad = (Ar1 != 0.f) || (Ar2 != 0.f) || (Ar3 != 0.f)
             || ((A15 != 0.f) && ((lane & 15) >= 1))
             || ((A31 != 0.f) && (lane >= 33));
    const bool fastAll = (__ballot(bad) == 0ull);

    float logoff = 0.f;
    {   // t = 0 emission (letter always valid; n >= 128) + renorm to 2^60
        int lm0 = (int)lets[0];
        const float* bp = smem + lm0*768 + lane12;
        float4 q0 = ((const float4*)bp)[0], q1 = ((const float4*)bp)[1], q2 = ((const float4*)bp)[2];
        Pm0 *= mkv2(q0.x,q0.y); Pm1 *= mkv2(q0.z,q0.w); Pm2 *= mkv2(q1.x,q1.y);
        Pi0 *= mkv2(q1.z,q1.w); Pi1 *= mkv2(q2.x,q2.y); Pi2 *= mkv2(q2.z,q2.w);
        pi384 *= smem[L_ES + lm0];
        RENORM;
    }

    // rotating 3-buffer / 3-letter-register pipeline
    Buf bA, bB, bC;
    FILL((int)lets[1], bA);
    FILL((int)lets[2], bB);
    int lA = (int)lets[3], lB = (int)lets[4], lC = (int)lets[5];

    const int total = n - 1;           // steps t = 1 .. n-1 (t >= n are exact no-ops)
    const int bodies = total / 6;
    const int rem = total - bodies*6;
    int t = 1;
    if (fastAll) SCANLOOP(1);
    else         SCANLOOP(0);

    v2f sv = Pm0 + Pm1 + Pm2 + Pi0 + Pi1 + Pi2;
    float s = sv.x + sv.y + ((lane == 63) ? pi384 : 0.f);
    s += fdpp<0x111>(s); s += fdpp<0x112>(s); s += fdpp<0x114>(s); s += fdpp<0x118>(s);
    s += fdpp<0x142>(s); s += fdpp<0x143>(s);
    if (lane == 63) out[b] = lsc[0] * (__logf(s) + logoff);
}

extern "C" void kernel_launch(void* const* d_in, const int* in_sizes, int n_in,
                              void* d_out, int out_size, void* d_ws, size_t ws_size,
                              hipStream_t stream)
{
    const float* ps   = (const float*)d_in[0];  // precursor_seq (384,21)
    const float* iseq = (const float*)d_in[1];  // insert_seq (385,21)
    const float* ins  = (const float*)d_in[2];  // insert (384,3,2)
    const float* del  = (const float*)d_in[3];  // delete (384,3,2)
    const float* seq  = (const float*)d_in[4];  // seq_data (64,256,21)
    const float* lsc  = (const float*)d_in[5];  // local_scale (1,)
    float* out = (float*)d_out;
    hmm_fused<<<64, 256, 0, stream>>>(ps, iseq, ins, del, seq, lsc, out);
}

// Round 6
// 106.084 us; speedup vs baseline: 1.2365x; 1.0259x over previous
//
#include <hip/hip_runtime.h>

// ProfileHMM forward on MI355X — single fused kernel.
// Each block (256 threads) builds HMM coefficients in LDS, then wave 0 runs
// the sequential scan (weighted prefix recurrence over 384 positions + scalar
// state I_384). Steps t>=n are exact no-ops (unit row sums, unit emissions) =>
// early exit at the sequence length. Rotating 3-buffer emission pipeline with
// per-iteration sched_barrier pinning the LDS prefetch distance; renorm every
// 12 steps by an exact power-of-2 scale (exponent-only, branchless, no div).

#define NEGC (-1.0e32f)

typedef float v2f __attribute__((ext_vector_type(2)));

#if __has_builtin(__builtin_elementwise_fma)
#define VFMA(a,b,c) __builtin_elementwise_fma((a),(b),(c))
#else
static __device__ __forceinline__ v2f VFMA(v2f a, v2f b, v2f c) {
    v2f r; r.x = fmaf(a.x,b.x,c.x); r.y = fmaf(a.y,b.y,c.y); return r;
}
#endif
#if __has_builtin(__builtin_elementwise_max)
#define VMAX(a,b) __builtin_elementwise_max((a),(b))
#else
static __device__ __forceinline__ v2f VMAX(v2f a, v2f b) {
    v2f r; r.x = fmaxf(a.x,b.x); r.y = fmaxf(a.y,b.y); return r;
}
#endif
static __device__ __forceinline__ v2f mkv2(float a, float b) { v2f r; r.x = a; r.y = b; return r; }

#if __has_builtin(__builtin_amdgcn_sched_barrier)
#define SCHED_FENCE() __builtin_amdgcn_sched_barrier(0x401)   /* ALU+trans may cross; DS/VMEM pinned */
#else
#define SCHED_FENCE()
#endif

template<int CTRL>
__device__ __forceinline__ float fdpp(float x) {
    union { float f; int i; } u, r;
    u.f = x;
    r.i = __builtin_amdgcn_update_dpp(0, u.i, CTRL, 0xF, 0xF, true);
    return r.f;
}
// whole-wave shift right by 1 lane, lane0 <- 0 (gfx9 DPP wave_shr:1)
__device__ __forceinline__ float wsr1(float x) { return fdpp<0x138>(x); }

// LDS float layout (scan phase): TAB [21][64][12]=16128, ES 16128..16152,
// lets bytes at float-offset 16152 (264 B). Setup scratch aliases 0..~10010.
#define L_TAB   0
#define L_ES    16128
#define L_LETS  16152
#define L_TOTAL 16224

#define S_RN    0
#define S_UN    2304
#define S_EWS   4608
#define S_ETMM  4993
#define S_ETII  5378
#define S_CS    5763
#define S_QA    6148
#define S_D2    6533
#define S_AEM   6917
#define S_AEI   7302
#define S_DMA   7687
#define S_DMB   8072
#define S_DIA   8457
#define S_DIB   8842
#define S_RAW   9227
#define S_RED   9998

struct Buf { v2f em0, em1, em2, ei0, ei1, ei2; float es; };

// exponent-only renorm: scale all states by exactly 2^(197-E) where E is the
// biased exponent of the wave max; accumulate integer ksum += (197-E).
// True log-offset correction applied once at the end: -ksum*ln2.
#define RENORM do { \
    v2f mv_ = VMAX(VMAX(Pm0,Pm1), VMAX(Pm2, VMAX(Pi0, VMAX(Pi1,Pi2)))); \
    float mxr_ = fmaxf(fmaxf(mv_.x, mv_.y), pi384); \
    mxr_ = fmaxf(mxr_, fdpp<0x111>(mxr_)); \
    mxr_ = fmaxf(mxr_, fdpp<0x112>(mxr_)); \
    mxr_ = fmaxf(mxr_, fdpp<0x114>(mxr_)); \
    mxr_ = fmaxf(mxr_, fdpp<0x118>(mxr_)); \
    mxr_ = fmaxf(mxr_, fdpp<0x142>(mxr_)); \
    mxr_ = fmaxf(mxr_, fdpp<0x143>(mxr_)); \
    union { float f; int i; } ub_; ub_.f = mxr_; \
    int bits_ = __builtin_amdgcn_readlane(ub_.i, 63); \
    int E_ = (bits_ >> 23) & 0xff; \
    E_ = (E_ < 71) ? 71 : E_; \
    ksum += 197 - E_; \
    union { int i; float f; } us_; us_.i = (324 - E_) << 23; \
    float sc_ = us_.f; \
    Pm0 *= sc_; Pm1 *= sc_; Pm2 *= sc_; Pi0 *= sc_; Pi1 *= sc_; Pi2 *= sc_; pi384 *= sc_; \
} while (0)

#define FILL(LM, E) do { \
    int lmv_ = (LM); \
    int lmc_ = lmv_ > 20 ? 20 : lmv_; \
    const float* bp_ = smem + lmc_*768 + lane12; \
    float4 q0_ = ((const float4*)bp_)[0], q1_ = ((const float4*)bp_)[1], q2_ = ((const float4*)bp_)[2]; \
    E.em0 = mkv2(q0_.x,q0_.y); E.em1 = mkv2(q0_.z,q0_.w); E.em2 = mkv2(q1_.x,q1_.y); \
    E.ei0 = mkv2(q1_.z,q1_.w); E.ei1 = mkv2(q2_.x,q2_.y); E.ei2 = mkv2(q2_.z,q2_.w); \
    E.es = smem[L_ES + lmv_]; \
} while (0)

#define CORE(CUR, FAST) do { \
    float apx_ = wsr1(Pm2.y); \
    float oldPm_ = Pm2.y; \
    v2f Ap0_ = mkv2(apx_, Pm0.x), Ap1_ = mkv2(Pm0.y, Pm1.x), Ap2_ = mkv2(Pm1.y, Pm2.x); \
    v2f E0_ = VFMA(Pi0, Cei0, Ap0_*Cem0); \
    v2f E1_ = VFMA(Pi1, Cei1, Ap1_*Cem1); \
    v2f E2_ = VFMA(Pi2, Cei2, Ap2_*Cem2); \
    float i0_ = E0_.x; \
    float i1_ = fmaf(w1, i0_, E0_.y); \
    float i2_ = fmaf(w2, i1_, E1_.x); \
    float i3_ = fmaf(w3, i2_, E1_.y); \
    float i4_ = fmaf(w4, i3_, E2_.x); \
    float i5_ = fmaf(w5, i4_, E2_.y); \
    float bb_, bx_; \
    if (FAST) { \
        float u_ = wsr1(i5_); \
        bb_ = fmaf(Ar0, u_, i5_);             /* only lane63's bb_ is consumed */ \
        bx_ = fmaf(Ar0s, wsr1(u_), u_);       /* == wsr1(bb_), shorter chain   */ \
    } else { \
        bb_ = i5_; \
        bb_ = fmaf(Ar0, fdpp<0x111>(bb_), bb_); \
        bb_ = fmaf(Ar1, fdpp<0x112>(bb_), bb_); \
        bb_ = fmaf(Ar2, fdpp<0x114>(bb_), bb_); \
        bb_ = fmaf(Ar3, fdpp<0x118>(bb_), bb_); \
        bb_ = fmaf(A15, fdpp<0x142>(bb_), bb_); \
        bb_ = fmaf(A31, fdpp<0x143>(bb_), bb_); \
        bx_ = wsr1(bb_); \
    } \
    v2f Rv0_ = mkv2(bx_, fmaf(pw1, bx_, i0_)); \
    v2f Rv1_ = mkv2(fmaf(pw2, bx_, i1_), fmaf(pw3, bx_, i2_)); \
    v2f Rv2_ = mkv2(fmaf(pw4, bx_, i3_), fmaf(pw5, bx_, i4_)); \
    v2f nm0_ = VFMA(Cgm0, Rv0_, VFMA(Pi0, Cdmb0, Ap0_*Cdma0)); \
    v2f nm1_ = VFMA(Cgm1, Rv1_, VFMA(Pi1, Cdmb1, Ap1_*Cdma1)); \
    v2f nm2_ = VFMA(Cgm2, Rv2_, VFMA(Pi2, Cdmb2, Ap2_*Cdma2)); \
    v2f ni0_ = VFMA(Cgi0, Rv0_, VFMA(Pi0, Cdib0, Ap0_*Cdia0)); \
    v2f ni1_ = VFMA(Cgi1, Rv1_, VFMA(Pi1, Cdib1, Ap1_*Cdia1)); \
    v2f ni2_ = VFMA(Cgi2, Rv2_, VFMA(Pi2, Cdib2, Ap2_*Cdia2)); \
    float np_ = ((oldPm_ + pi384) + bb_) * CUR.es; /* cDIA[384]==cDIB[384]==1 */ \
    Pm0 = nm0_*CUR.em0; Pm1 = nm1_*CUR.em1; Pm2 = nm2_*CUR.em2; \
    Pi0 = ni0_*CUR.ei0; Pi1 = ni1_*CUR.ei1; Pi2 = ni2_*CUR.ei2; \
    pi384 = np_; \
} while (0)

#define ITER(BA,BB,BC,LA,LB,LC,TIDX,FAST) do { \
    FILL(LA, BC); \
    LA = (int)lets[(TIDX)+5]; \
    CORE(BA, FAST); \
    SCHED_FENCE(); \
} while (0)

#define SCANLOOP(FAST) do { \
    for (int it = 0; it < bodies; ++it, t += 12) { \
        ITER(bA,bB,bC,lA,lB,lC,t,FAST); \
        ITER(bB,bC,bA,lB,lC,lA,t+1,FAST); \
        ITER(bC,bA,bB,lC,lA,lB,t+2,FAST); \
        ITER(bA,bB,bC,lA,lB,lC,t+3,FAST); \
        ITER(bB,bC,bA,lB,lC,lA,t+4,FAST); \
        ITER(bC,bA,bB,lC,lA,lB,t+5,FAST); \
        ITER(bA,bB,bC,lA,lB,lC,t+6,FAST); \
        ITER(bB,bC,bA,lB,lC,lA,t+7,FAST); \
        ITER(bC,bA,bB,lC,lA,lB,t+8,FAST); \
        ITER(bA,bB,bC,lA,lB,lC,t+9,FAST); \
        ITER(bB,bC,bA,lB,lC,lA,t+10,FAST); \
        ITER(bC,bA,bB,lC,lA,lB,t+11,FAST); \
        RENORM; \
    } \
    if (rem > 0)  { ITER(bA,bB,bC,lA,lB,lC,t,FAST); ++t; } \
    if (rem > 1)  { ITER(bB,bC,bA,lB,lC,lA,t,FAST); ++t; } \
    if (rem > 2)  { ITER(bC,bA,bB,lC,lA,lB,t,FAST); ++t; } \
    if (rem > 3)  { ITER(bA,bB,bC,lA,lB,lC,t,FAST); ++t; } \
    if (rem > 4)  { ITER(bB,bC,bA,lB,lC,lA,t,FAST); ++t; } \
    if (rem > 5)  { ITER(bC,bA,bB,lC,lA,lB,t,FAST); ++t; } \
    if (rem > 6)  { ITER(bA,bB,bC,lA,lB,lC,t,FAST); ++t; } \
    if (rem > 7)  { ITER(bB,bC,bA,lB,lC,lA,t,FAST); ++t; } \
    if (rem > 8)  { ITER(bC,bA,bB,lC,lA,lB,t,FAST); ++t; } \
    if (rem > 9)  { ITER(bA,bB,bC,lA,lB,lC,t,FAST); ++t; } \
    if (rem > 10) { ITER(bB,bC,bA,lB,lC,lA,t,FAST); ++t; } \
} while (0)

__global__ __launch_bounds__(256, 1) void hmm_fused(
    const float* __restrict__ ps, const float* __restrict__ iseq,
    const float* __restrict__ rr, const float* __restrict__ uu,
    const float* __restrict__ seq, const float* __restrict__ lsc,
    float* __restrict__ out)
{
    __shared__ float smem[L_TOTAL];
    const int tid = threadIdx.x;
    const int lane = tid & 63;
    const int wvid = tid >> 6;
    const int b = blockIdx.x;
    unsigned char* lets = (unsigned char*)(smem + L_LETS);

    float* rn   = smem + S_RN;
    float* un   = smem + S_UN;
    float* ews  = smem + S_EWS;
    float* etmm = smem + S_ETMM;
    float* etii = smem + S_ETII;
    float* Cs   = smem + S_CS;
    float* qa   = smem + S_QA;
    float* d2s  = smem + S_D2;
    float* cAEM = smem + S_AEM;
    float* cAEI = smem + S_AEI;
    float* cDMA = smem + S_DMA;
    float* cDMB = smem + S_DMB;
    float* cDIA = smem + S_DIA;
    float* cDIB = smem + S_DIB;
    float* rawv = smem + S_RAW;
    float* red  = smem + S_RED;

    // ---- letters + row log-softmax of r,u ----
    {
        const float* p = seq + (size_t)b*5376 + tid*21;
        float s = 0.f, wsum = 0.f;
        #pragma unroll
        for (int a = 0; a < 21; ++a) { float v = p[a]; s += v; wsum += v*(float)a; }
        lets[tid] = (s > 0.5f) ? (unsigned char)(int)(wsum + 0.5f) : (unsigned char)21;
        if (tid < 8) lets[256 + tid] = (unsigned char)21;
    }
    for (int row = tid; row < 1152; row += 256) {
        float a = rr[row*2], c = rr[row*2+1];
        float mx = fmaxf(a, c);
        float l = mx + __logf(__expf(a-mx) + __expf(c-mx));
        rn[row*2] = a - l; rn[row*2+1] = c - l;
        a = uu[row*2]; c = uu[row*2+1];
        mx = fmaxf(a, c);
        l = mx + __logf(__expf(a-mx) + __expf(c-mx));
        un[row*2] = a - l; un[row*2+1] = c - l;
    }
    __syncthreads();
    for (int m = tid; m < 384; m += 256) {
        float d = rn[(m*3+2)*2+0] + un[(m*3+2)*2+1];
        d2s[m] = d;
        ews[m] = __expf(d);
        etmm[m] = __expf(rn[(m*3+2)*2+0] + un[(m*3+2)*2+0]);
        etii[m] = __expf(rn[(m*3+2)*2+1]);
    }
    if (tid == 0) { ews[384] = 0.f; etmm[384] = 0.f; etii[384] = 1.f; }
    __syncthreads();
    // ---- wave0: Cs additive scan; wave1: qa weighted reverse scan ----
    if (tid < 64) {
        float incl[6]; float z = 0.f;
        #pragma unroll
        for (int i = 0; i < 6; ++i) { z += d2s[lane*6+i]; incl[i] = z; }
        float tot = z;
        #pragma unroll
        for (int d = 1; d < 64; d <<= 1) { float q = __shfl_up(tot, d); if (lane >= d) tot += q; }
        float excl = __shfl_up(tot, 1); if (lane == 0) excl = 0.f;
        #pragma unroll
        for (int i = 0; i < 6; ++i) Cs[lane*6+i+1] = excl + incl[i];
        if (lane == 0) Cs[0] = 0.f;
    } else if (tid < 128) {
        float wv6[6], xv[6], incl[6];
        #pragma unroll
        for (int i = 0; i < 6; ++i) {
            int s = 384 - (lane*6 + i);
            wv6[i] = ews[s]; xv[i] = etii[s] + etmm[s];
        }
        float z = 0.f, Wl = 1.f;
        #pragma unroll
        for (int i = 0; i < 6; ++i) { z = fmaf(wv6[i], z, xv[i]); incl[i] = z; Wl *= wv6[i]; }
        float val = z, wt = Wl;
        #pragma unroll
        for (int d = 1; d < 64; d <<= 1) {
            float pv = __shfl_up(val, d); float pwv = __shfl_up(wt, d);
            if (lane >= d) { val = fmaf(wt, pv, val); wt *= pwv; }
        }
        float excl = __shfl_up(val, 1); if (lane == 0) excl = 0.f;
        float pp = 1.f;
        #pragma unroll
        for (int i = 0; i < 6; ++i) {
            pp *= wv6[i];
            qa[383 - (lane*6 + i)] = fmaf(excl, pp, incl[i]);
        }
        if (lane == 0) qa[384] = 0.f;
    }
    __syncthreads();
    // ---- per-source coefficients + raw initial vector ----
    for (int k = tid; k < 769; k += 256) {
        int g = (k < 384) ? 0 : 1;
        int m = (k < 384) ? k : (k - 384);
        int s = m + 1 - g;
        float ss, sd, smv, si;
        if (s <= 383) {
            int base = (s*3 + g)*2;
            ss = rn[base+0]; si = rn[base+1];
            smv = un[base+0]; sd = un[base+1];
        } else { ss = NEGC; si = 0.f; smv = 0.f; sd = NEGC; }
        float d0 = (s <= 383) ? (ss + smv) : NEGC;
        float d1 = si;
        float q = qa[s];
        float lq = (q > 0.f) ? __logf(q) : -1.0e30f;
        float ch = ss + sd + lq;
        float mx = fmaxf(fmaxf(d0, d1), ch);
        float Z = mx + __logf(__expf(d0-mx) + __expf(d1-mx) + __expf(ch-mx));
        float we = __expf(ss + sd - Z);
        float w0 = __expf(d0 - Z);
        float w1v = __expf(d1 - Z);
        if (g == 0) { cAEM[s] = we; cDMA[s] = w0; cDIA[s] = w1v; }
        else        { cAEI[s] = we; cDMB[s] = w0; cDIB[s] = w1v; }
    }
    if (tid == 0) { cAEM[0] = 0.f; cDMA[0] = 0.f; cDIA[0] = 0.f; }
    {
        float r000 = rn[0], r001 = rn[1];
        float u000 = un[0], u001 = un[1];
        for (int k = tid; k < 769; k += 256) {
            int g = (k < 384) ? 0 : 1;
            int m = (k < 384) ? k : (k - 384);
            float v;
            if (m == 0) v = g ? r001 : (r000 + u000);
            else {
                float tt = g ? ((m <= 383) ? rn[(m*3+2)*2+1] : 0.f)
                             : (rn[(m*3+2)*2+0] + un[(m*3+2)*2+0]);
                v = r000 + u001 - Cs[1] + Cs[m] + tt;
            }
            rawv[k] = v;
        }
    }
    __syncthreads();
    // ---- block logsumexp of rawv; p0 in place ----
    {
        float lmax = -3.0e38f;
        for (int k = tid; k < 769; k += 256) lmax = fmaxf(lmax, rawv[k]);
        #pragma unroll
        for (int d = 1; d < 64; d <<= 1) lmax = fmaxf(lmax, __shfl_xor(lmax, d));
        if (lane == 0) red[wvid] = lmax;
    }
    __syncthreads();
    {
        float gmax = fmaxf(fmaxf(red[0], red[1]), fmaxf(red[2], red[3]));
        float lsum = 0.f;
        for (int k = tid; k < 769; k += 256) lsum += __expf(rawv[k] - gmax);
        #pragma unroll
        for (int d = 1; d < 64; d <<= 1) lsum += __shfl_xor(lsum, d);
        if (lane == 0) red[4 + wvid] = lsum;
        __syncthreads();
        float lse = gmax + __logf(red[4] + red[5] + red[6] + red[7]);
        for (int k = tid; k < 769; k += 256) rawv[k] = __expf(rawv[k] - lse);
    }
    __syncthreads();
    // ---- load per-lane regs (only wave0's survive) ----
    const int j0 = lane*6;
    const int lane12 = lane*12;
    v2f Cem0=mkv2(cAEM[j0],cAEM[j0+1]), Cem1=mkv2(cAEM[j0+2],cAEM[j0+3]), Cem2=mkv2(cAEM[j0+4],cAEM[j0+5]);
    v2f Cei0=mkv2(cAEI[j0],cAEI[j0+1]), Cei1=mkv2(cAEI[j0+2],cAEI[j0+3]), Cei2=mkv2(cAEI[j0+4],cAEI[j0+5]);
    v2f Cdma0=mkv2(cDMA[j0],cDMA[j0+1]), Cdma1=mkv2(cDMA[j0+2],cDMA[j0+3]), Cdma2=mkv2(cDMA[j0+4],cDMA[j0+5]);
    v2f Cdmb0=mkv2(cDMB[j0],cDMB[j0+1]), Cdmb1=mkv2(cDMB[j0+2],cDMB[j0+3]), Cdmb2=mkv2(cDMB[j0+4],cDMB[j0+5]);
    v2f Cdia0=mkv2(cDIA[j0],cDIA[j0+1]), Cdia1=mkv2(cDIA[j0+2],cDIA[j0+3]), Cdia2=mkv2(cDIA[j0+4],cDIA[j0+5]);
    v2f Cdib0=mkv2(cDIB[j0],cDIB[j0+1]), Cdib1=mkv2(cDIB[j0+2],cDIB[j0+3]), Cdib2=mkv2(cDIB[j0+4],cDIB[j0+5]);
    v2f Cgm0=mkv2(etmm[j0],etmm[j0+1]), Cgm1=mkv2(etmm[j0+2],etmm[j0+3]), Cgm2=mkv2(etmm[j0+4],etmm[j0+5]);
    v2f Cgi0=mkv2(etii[j0],etii[j0+1]), Cgi1=mkv2(etii[j0+2],etii[j0+3]), Cgi2=mkv2(etii[j0+4],etii[j0+5]);
    v2f Pm0=mkv2(rawv[j0],rawv[j0+1]), Pm1=mkv2(rawv[j0+2],rawv[j0+3]), Pm2=mkv2(rawv[j0+4],rawv[j0+5]);
    v2f Pi0=mkv2(rawv[384+j0],rawv[384+j0+1]), Pi1=mkv2(rawv[384+j0+2],rawv[384+j0+3]), Pi2=mkv2(rawv[384+j0+4],rawv[384+j0+5]);
    float pi384 = rawv[768];
    const float W0=ews[j0], w1=ews[j0+1], w2=ews[j0+2], w3=ews[j0+3], w4=ews[j0+4], w5=ews[j0+5];
    __syncthreads();
    // ---- emission table build (overwrites setup scratch) ----
    for (int row = tid; row < 769; row += 256) {
        const float* src = (row < 384) ? (ps + row*21) : (iseq + (row-384)*21);
        float mx = -3.0e38f;
        for (int a = 0; a < 21; ++a) mx = fmaxf(mx, src[a]);
        float sm2 = 0.f;
        for (int a = 0; a < 21; ++a) sm2 += __expf(src[a]-mx);
        float inv = 1.0f / sm2;
        if (row < 768) {
            int j = (row < 384) ? row : (row - 384);
            int slot = (j/6)*12 + ((row < 384) ? 0 : 6) + (j%6);
            float* dst = smem + L_TAB + slot;
            for (int a = 0; a < 21; ++a) dst[a*768] = __expf(src[a]-mx)*inv;
        } else {
            for (int a = 0; a < 21; ++a) smem[L_ES + a] = __expf(src[a]-mx)*inv;
            smem[L_ES + 21] = 1.0f; smem[L_ES + 22] = 1.0f; smem[L_ES + 23] = 1.0f;
        }
    }
    __syncthreads();
    if (wvid != 0) return;

    // ================= wave 0: the sequential scan =================
    int n = 0;
    #pragma unroll
    for (int c = 0; c < 4; ++c)
        n += __popcll(__ballot(lets[c*64 + lane] != (unsigned char)21));

    const float pw1 = W0, pw2 = pw1*w1, pw3 = pw2*w2, pw4 = pw3*w3, pw5 = pw4*w4;
    const float W = pw5*w5;
    float p_ = W;
    const float Ar0 = p_;
    const float Ar0s = wsr1(Ar0);
    { float q = __shfl_up(p_, 1); p_ *= q; } const float Ar1 = p_;
    { float q = __shfl_up(p_, 2); p_ *= q; } const float Ar2 = p_;
    { float q = __shfl_up(p_, 4); p_ *= q; } const float Ar3 = p_;
    float prefR = W;
    #pragma unroll
    for (int d = 1; d < 16; d <<= 1) { float q = __shfl_up(prefR, d); if ((lane & 15) >= d) prefR *= q; }
    const int rw = lane >> 4;
    const float A15 = (rw == 1 || rw == 3) ? prefR : 0.f;
    const float s47 = __shfl(prefR, 47);
    const float A31 = (rw == 2) ? prefR : ((rw == 3) ? prefR * s47 : 0.f);
    bool bad = (Ar1 != 0.f) || (Ar2 != 0.f) || (Ar3 != 0.f)
             || ((A15 != 0.f) && ((lane & 15) >= 1))
             || ((A31 != 0.f) && (lane >= 33));
    const bool fastAll = (__ballot(bad) == 0ull);

    int ksum = 0;
    {   // t = 0 emission (letter always valid; n >= 128) + exponent renorm
        int lm0 = (int)lets[0];
        const float* bp = smem + lm0*768 + lane12;
        float4 q0 = ((const float4*)bp)[0], q1 = ((const float4*)bp)[1], q2 = ((const float4*)bp)[2];
        Pm0 *= mkv2(q0.x,q0.y); Pm1 *= mkv2(q0.z,q0.w); Pm2 *= mkv2(q1.x,q1.y);
        Pi0 *= mkv2(q1.z,q1.w); Pi1 *= mkv2(q2.x,q2.y); Pi2 *= mkv2(q2.z,q2.w);
        pi384 *= smem[L_ES + lm0];
        RENORM;
    }

    // rotating 3-buffer / 3-letter-register pipeline
    Buf bA, bB, bC;
    FILL((int)lets[1], bA);
    FILL((int)lets[2], bB);
    int lA = (int)lets[3], lB = (int)lets[4], lC = (int)lets[5];

    const int total = n - 1;           // steps t = 1 .. n-1 (t >= n are exact no-ops)
    const int bodies = total / 12;
    const int rem = total - bodies*12;
    int t = 1;
    if (fastAll) SCANLOOP(1);
    else         SCANLOOP(0);

    v2f sv = Pm0 + Pm1 + Pm2 + Pi0 + Pi1 + Pi2;
    float s = sv.x + sv.y + ((lane == 63) ? pi384 : 0.f);
    s += fdpp<0x111>(s); s += fdpp<0x112>(s); s += fdpp<0x114>(s); s += fdpp<0x118>(s);
    s += fdpp<0x142>(s); s += fdpp<0x143>(s);
    if (lane == 63) out[b] = lsc[0] * (__logf(s) - (float)ksum * 0.69314718055994531f);
}

extern "C" void kernel_launch(void* const* d_in, const int* in_sizes, int n_in,
                              void* d_out, int out_size, void* d_ws, size_t ws_size,
                              hipStream_t stream)
{
    const float* ps   = (const float*)d_in[0];  // precursor_seq (384,21)
    const float* iseq = (const float*)d_in[1];  // insert_seq (385,21)
    const float* ins  = (const float*)d_in[2];  // insert (384,3,2)
    const float* del  = (const float*)d_in[3];  // delete (384,3,2)
    const float* seq  = (const float*)d_in[4];  // seq_data (64,256,21)
    const float* lsc  = (const float*)d_in[5];  // local_scale (1,)
    float* out = (float*)d_out;
    hmm_fused<<<64, 256, 0, stream>>>(ps, iseq, ins, del, seq, lsc, out);
}

// Round 7
// 104.953 us; speedup vs baseline: 1.2499x; 1.0108x over previous
//
#include <hip/hip_runtime.h>

// ProfileHMM forward on MI355X — single fused kernel.
// Each block (256 threads) builds HMM coefficients in LDS, then wave 0 runs
// the sequential scan (weighted prefix recurrence over 384 positions + scalar
// state I_384). Steps t>=n are exact no-ops (unit row sums, unit emissions) =>
// early exit at sequence length. 4-buffer rotating emission pipeline (LDS
// prefetch issued 3 iterations ahead, pinned by sched_barrier), letter+es
// packed into one u32 per step, (j,j+3) pair packing so shifted-pair reuse
// (Ap_B==Pm_A, Ap_C==Pm_B) kills cross-element movs, renorm every 12 steps by
// exact power-of-2 scale (exponent arithmetic only).

#define NEGC (-1.0e32f)

typedef float v2f __attribute__((ext_vector_type(2)));

#if __has_builtin(__builtin_elementwise_fma)
#define VFMA(a,b,c) __builtin_elementwise_fma((a),(b),(c))
#else
static __device__ __forceinline__ v2f VFMA(v2f a, v2f b, v2f c) {
    v2f r; r.x = fmaf(a.x,b.x,c.x); r.y = fmaf(a.y,b.y,c.y); return r;
}
#endif
#if __has_builtin(__builtin_elementwise_max)
#define VMAX(a,b) __builtin_elementwise_max((a),(b))
#else
static __device__ __forceinline__ v2f VMAX(v2f a, v2f b) {
    v2f r; r.x = fmaxf(a.x,b.x); r.y = fmaxf(a.y,b.y); return r;
}
#endif
static __device__ __forceinline__ v2f mkv2(float a, float b) { v2f r; r.x = a; r.y = b; return r; }

#if __has_builtin(__builtin_amdgcn_sched_barrier)
#define SCHED_FENCE() __builtin_amdgcn_sched_barrier(0x401)   /* ALU may cross; DS/VMEM pinned */
#else
#define SCHED_FENCE()
#endif

template<int CTRL>
__device__ __forceinline__ float fdpp(float x) {
    union { float f; int i; } u, r;
    u.f = x;
    r.i = __builtin_amdgcn_update_dpp(0, u.i, CTRL, 0xF, 0xF, true);
    return r.f;
}
// whole-wave shift right by 1 lane, lane0 <- 0 (gfx9 DPP wave_shr:1)
__device__ __forceinline__ float wsr1(float x) { return fdpp<0x138>(x); }

// LDS float layout (scan phase): TAB [21 letters][64 lanes][12] = 16128,
// ESL (packed es|letter per step) 16128..16384. Total exactly 16384 floats.
// Setup scratch (0..~10104) is overwritten by TAB after consumption.
#define L_TAB   0
#define L_ESL   16128
#define L_TOTAL 16384

#define S_RN    0
#define S_UN    2304
#define S_EWS   4608
#define S_ETMM  4993
#define S_ETII  5378
#define S_CS    5763
#define S_QA    6148
#define S_D2    6533
#define S_AEM   6917
#define S_AEI   7302
#define S_DMA   7687
#define S_DMB   8072
#define S_DIA   8457
#define S_DIB   8842
#define S_RAW   9227
#define S_RED   9998
#define S_LETS  10016   /* 66 floats = 264 bytes of letters */
#define S_ES    10082   /* 22 floats: es per letter (insert row 384) */

struct Buf { v2f em0, em1, em2, ei0, ei1, ei2; float es; };

// exponent-only renorm: scale all states by exactly 2^(197-E), E = biased
// exponent of wave max; ksum accumulates (197-E); final fix = -ksum*ln2.
#define RENORM do { \
    v2f mv_ = VMAX(VMAX(PmA,PmB), VMAX(PmC, VMAX(PiA, VMAX(PiB,PiC)))); \
    float mxr_ = fmaxf(fmaxf(mv_.x, mv_.y), pi384); \
    mxr_ = fmaxf(mxr_, fdpp<0x111>(mxr_)); \
    mxr_ = fmaxf(mxr_, fdpp<0x112>(mxr_)); \
    mxr_ = fmaxf(mxr_, fdpp<0x114>(mxr_)); \
    mxr_ = fmaxf(mxr_, fdpp<0x118>(mxr_)); \
    mxr_ = fmaxf(mxr_, fdpp<0x142>(mxr_)); \
    mxr_ = fmaxf(mxr_, fdpp<0x143>(mxr_)); \
    union { float f; int i; } ub_; ub_.f = mxr_; \
    int bits_ = __builtin_amdgcn_readlane(ub_.i, 63); \
    int E_ = (bits_ >> 23) & 0xff; \
    E_ = (E_ < 71) ? 71 : E_; \
    ksum += 197 - E_; \
    union { int i; float f; } us_; us_.i = (324 - E_) << 23; \
    float sc_ = us_.f; \
    PmA *= sc_; PmB *= sc_; PmC *= sc_; PiA *= sc_; PiB *= sc_; PiC *= sc_; pi384 *= sc_; \
} while (0)

#define FILLE(E, EV) do { \
    int lm_ = (EV) & 0xff; \
    const float* bp_ = smem + lm_*768 + lane12; \
    float4 q0_ = ((const float4*)bp_)[0], q1_ = ((const float4*)bp_)[1], q2_ = ((const float4*)bp_)[2]; \
    E.em0 = mkv2(q0_.x,q0_.y); E.em1 = mkv2(q0_.z,q0_.w); E.em2 = mkv2(q1_.x,q1_.y); \
    E.ei0 = mkv2(q1_.z,q1_.w); E.ei1 = mkv2(q2_.x,q2_.y); E.ei2 = mkv2(q2_.z,q2_.w); \
    union { int i; float f; } ue_; ue_.i = (EV) & 0xffffff00; E.es = ue_.f; \
} while (0)

// pairs hold positions (j, j+3): A=(0,3) B=(1,4) C=(2,5).
// Shifted pairs: Ap_A=(prev5, 2)=(wsr1(PmC.y), PmC.x); Ap_B=PmA; Ap_C=PmB.
#define CORE(CUR, FAST) do { \
    float apx_ = wsr1(PmC.y); \
    float oldPm_ = PmC.y; \
    v2f ApA_ = mkv2(apx_, PmC.x); \
    v2f EA_ = VFMA(PiA, CeiA, ApA_*CemA); \
    v2f EB_ = VFMA(PiB, CeiB, PmA*CemB); \
    v2f EC_ = VFMA(PiC, CeiC, PmB*CemC); \
    float i0_ = EA_.x; \
    float i1_ = fmaf(w1, i0_, EB_.x); \
    float i2_ = fmaf(w2, i1_, EC_.x); \
    float i3_ = fmaf(w3, i2_, EA_.y); \
    float i4_ = fmaf(w4, i3_, EB_.y); \
    float i5_ = fmaf(w5, i4_, EC_.y); \
    float bb_, bx_; \
    if (FAST) { \
        float u_ = wsr1(i5_); \
        bb_ = fmaf(Ar0, u_, i5_);             /* only lane63's bb_ consumed */ \
        bx_ = fmaf(Ar0s, wsr1(u_), u_);       /* == wsr1(bb_), shorter chain */ \
    } else { \
        bb_ = i5_; \
        bb_ = fmaf(Ar0, fdpp<0x111>(bb_), bb_); \
        bb_ = fmaf(Ar1, fdpp<0x112>(bb_), bb_); \
        bb_ = fmaf(Ar2, fdpp<0x114>(bb_), bb_); \
        bb_ = fmaf(Ar3, fdpp<0x118>(bb_), bb_); \
        bb_ = fmaf(A15, fdpp<0x142>(bb_), bb_); \
        bb_ = fmaf(A31, fdpp<0x143>(bb_), bb_); \
        bx_ = wsr1(bb_); \
    } \
    v2f RA_ = mkv2(bx_, fmaf(pw3, bx_, i2_)); \
    v2f RB_ = mkv2(fmaf(pw1, bx_, i0_), fmaf(pw4, bx_, i3_)); \
    v2f RC_ = mkv2(fmaf(pw2, bx_, i1_), fmaf(pw5, bx_, i4_)); \
    v2f nmA_ = VFMA(CgmA, RA_, VFMA(PiA, CdmbA, ApA_*CdmaA)); \
    v2f nmB_ = VFMA(CgmB, RB_, VFMA(PiB, CdmbB, PmA*CdmaB)); \
    v2f nmC_ = VFMA(CgmC, RC_, VFMA(PiC, CdmbC, PmB*CdmaC)); \
    v2f niA_ = VFMA(CgiA, RA_, VFMA(PiA, CdibA, ApA_*CdiaA)); \
    v2f niB_ = VFMA(CgiB, RB_, VFMA(PiB, CdibB, PmA*CdiaB)); \
    v2f niC_ = VFMA(CgiC, RC_, VFMA(PiC, CdibC, PmB*CdiaC)); \
    float np_ = ((oldPm_ + pi384) + bb_) * CUR.es; /* cDIA[384]==cDIB[384]==1 */ \
    PmA = nmA_*CUR.em0; PmB = nmB_*CUR.em1; PmC = nmC_*CUR.em2; \
    PiA = niA_*CUR.ei0; PiB = niB_*CUR.ei1; PiC = niC_*CUR.ei2; \
    pi384 = np_; \
} while (0)

// ITER t: consume buf[t%4], fill buf[(t+3)%4] for step t+3 using esl[t+3]
// (loaded last iteration into eU); reload eU = esl[t+4].
#define ITER(BU, BF, T, FAST) do { \
    int ev_ = eU; \
    FILLE(BF, ev_); \
    { int ix_ = (T)+4; ix_ = ix_ > 255 ? 255 : ix_; eU = iesl[ix_]; } \
    CORE(BU, FAST); \
    SCHED_FENCE(); \
} while (0)

#define SCANLOOP(FAST) do { \
    for (int it = 0; it < bodies; ++it, t += 12) { \
        ITER(b1,b0,t,FAST);    ITER(b2,b1,t+1,FAST); \
        ITER(b3,b2,t+2,FAST);  ITER(b0,b3,t+3,FAST); \
        ITER(b1,b0,t+4,FAST);  ITER(b2,b1,t+5,FAST); \
        ITER(b3,b2,t+6,FAST);  ITER(b0,b3,t+7,FAST); \
        ITER(b1,b0,t+8,FAST);  ITER(b2,b1,t+9,FAST); \
        ITER(b3,b2,t+10,FAST); ITER(b0,b3,t+11,FAST); \
        RENORM; \
    } \
    if (rem > 0)  { ITER(b1,b0,t,FAST); ++t; } \
    if (rem > 1)  { ITER(b2,b1,t,FAST); ++t; } \
    if (rem > 2)  { ITER(b3,b2,t,FAST); ++t; } \
    if (rem > 3)  { ITER(b0,b3,t,FAST); ++t; } \
    if (rem > 4)  { ITER(b1,b0,t,FAST); ++t; } \
    if (rem > 5)  { ITER(b2,b1,t,FAST); ++t; } \
    if (rem > 6)  { ITER(b3,b2,t,FAST); ++t; } \
    if (rem > 7)  { ITER(b0,b3,t,FAST); ++t; } \
    if (rem > 8)  { ITER(b1,b0,t,FAST); ++t; } \
    if (rem > 9)  { ITER(b2,b1,t,FAST); ++t; } \
    if (rem > 10) { ITER(b3,b2,t,FAST); ++t; } \
} while (0)

__global__ __launch_bounds__(256, 1) void hmm_fused(
    const float* __restrict__ ps, const float* __restrict__ iseq,
    const float* __restrict__ rr, const float* __restrict__ uu,
    const float* __restrict__ seq, const float* __restrict__ lsc,
    float* __restrict__ out)
{
    __shared__ float smem[L_TOTAL];
    const int tid = threadIdx.x;
    const int lane = tid & 63;
    const int wvid = tid >> 6;
    const int b = blockIdx.x;
    unsigned char* lets = (unsigned char*)(smem + S_LETS);

    float* rn   = smem + S_RN;
    float* un   = smem + S_UN;
    float* ews  = smem + S_EWS;
    float* etmm = smem + S_ETMM;
    float* etii = smem + S_ETII;
    float* Cs   = smem + S_CS;
    float* qa   = smem + S_QA;
    float* d2s  = smem + S_D2;
    float* cAEM = smem + S_AEM;
    float* cAEI = smem + S_AEI;
    float* cDMA = smem + S_DMA;
    float* cDMB = smem + S_DMB;
    float* cDIA = smem + S_DIA;
    float* cDIB = smem + S_DIB;
    float* rawv = smem + S_RAW;
    float* red  = smem + S_RED;
    float* sES  = smem + S_ES;

    // ---- letters + row log-softmax of r,u ----
    {
        const float* p = seq + (size_t)b*5376 + tid*21;
        float s = 0.f, wsum = 0.f;
        #pragma unroll
        for (int a = 0; a < 21; ++a) { float v = p[a]; s += v; wsum += v*(float)a; }
        lets[tid] = (s > 0.5f) ? (unsigned char)(int)(wsum + 0.5f) : (unsigned char)21;
    }
    for (int row = tid; row < 1152; row += 256) {
        float a = rr[row*2], c = rr[row*2+1];
        float mx = fmaxf(a, c);
        float l = mx + __logf(__expf(a-mx) + __expf(c-mx));
        rn[row*2] = a - l; rn[row*2+1] = c - l;
        a = uu[row*2]; c = uu[row*2+1];
        mx = fmaxf(a, c);
        l = mx + __logf(__expf(a-mx) + __expf(c-mx));
        un[row*2] = a - l; un[row*2+1] = c - l;
    }
    __syncthreads();
    for (int m = tid; m < 384; m += 256) {
        float d = rn[(m*3+2)*2+0] + un[(m*3+2)*2+1];
        d2s[m] = d;
        ews[m] = __expf(d);
        etmm[m] = __expf(rn[(m*3+2)*2+0] + un[(m*3+2)*2+0]);
        etii[m] = __expf(rn[(m*3+2)*2+1]);
    }
    if (tid == 0) { ews[384] = 0.f; etmm[384] = 0.f; etii[384] = 1.f; }
    __syncthreads();
    // ---- wave0: Cs additive scan; wave1: qa weighted reverse scan ----
    if (tid < 64) {
        float incl[6]; float z = 0.f;
        #pragma unroll
        for (int i = 0; i < 6; ++i) { z += d2s[lane*6+i]; incl[i] = z; }
        float tot = z;
        #pragma unroll
        for (int d = 1; d < 64; d <<= 1) { float q = __shfl_up(tot, d); if (lane >= d) tot += q; }
        float excl = __shfl_up(tot, 1); if (lane == 0) excl = 0.f;
        #pragma unroll
        for (int i = 0; i < 6; ++i) Cs[lane*6+i+1] = excl + incl[i];
        if (lane == 0) Cs[0] = 0.f;
    } else if (tid < 128) {
        float wv6[6], xv[6], incl[6];
        #pragma unroll
        for (int i = 0; i < 6; ++i) {
            int s = 384 - (lane*6 + i);
            wv6[i] = ews[s]; xv[i] = etii[s] + etmm[s];
        }
        float z = 0.f, Wl = 1.f;
        #pragma unroll
        for (int i = 0; i < 6; ++i) { z = fmaf(wv6[i], z, xv[i]); incl[i] = z; Wl *= wv6[i]; }
        float val = z, wt = Wl;
        #pragma unroll
        for (int d = 1; d < 64; d <<= 1) {
            float pv = __shfl_up(val, d); float pwv = __shfl_up(wt, d);
            if (lane >= d) { val = fmaf(wt, pv, val); wt *= pwv; }
        }
        float excl = __shfl_up(val, 1); if (lane == 0) excl = 0.f;
        float pp = 1.f;
        #pragma unroll
        for (int i = 0; i < 6; ++i) {
            pp *= wv6[i];
            qa[383 - (lane*6 + i)] = fmaf(excl, pp, incl[i]);
        }
        if (lane == 0) qa[384] = 0.f;
    }
    __syncthreads();
    // ---- per-source coefficients + raw initial vector (+ es row by tid255) ----
    for (int k = tid; k < 769; k += 256) {
        int g = (k < 384) ? 0 : 1;
        int m = (k < 384) ? k : (k - 384);
        int s = m + 1 - g;
        float ss, sd, smv, si;
        if (s <= 383) {
            int base = (s*3 + g)*2;
            ss = rn[base+0]; si = rn[base+1];
            smv = un[base+0]; sd = un[base+1];
        } else { ss = NEGC; si = 0.f; smv = 0.f; sd = NEGC; }
        float d0 = (s <= 383) ? (ss + smv) : NEGC;
        float d1 = si;
        float q = qa[s];
        float lq = (q > 0.f) ? __logf(q) : -1.0e30f;
        float ch = ss + sd + lq;
        float mx = fmaxf(fmaxf(d0, d1), ch);
        float Z = mx + __logf(__expf(d0-mx) + __expf(d1-mx) + __expf(ch-mx));
        float we = __expf(ss + sd - Z);
        float w0 = __expf(d0 - Z);
        float w1v = __expf(d1 - Z);
        if (g == 0) { cAEM[s] = we; cDMA[s] = w0; cDIA[s] = w1v; }
        else        { cAEI[s] = we; cDMB[s] = w0; cDIB[s] = w1v; }
    }
    if (tid == 0) { cAEM[0] = 0.f; cDMA[0] = 0.f; cDIA[0] = 0.f; }
    if (tid == 255) {  // es row: softmax of insert row 384
        const float* src = iseq + 384*21;
        float mx = -3.0e38f;
        for (int a = 0; a < 21; ++a) mx = fmaxf(mx, src[a]);
        float sm2 = 0.f;
        for (int a = 0; a < 21; ++a) sm2 += __expf(src[a]-mx);
        float inv = 1.0f / sm2;
        for (int a = 0; a < 21; ++a) sES[a] = __expf(src[a]-mx)*inv;
    }
    {
        float r000 = rn[0], r001 = rn[1];
        float u000 = un[0], u001 = un[1];
        for (int k = tid; k < 769; k += 256) {
            int g = (k < 384) ? 0 : 1;
            int m = (k < 384) ? k : (k - 384);
            float v;
            if (m == 0) v = g ? r001 : (r000 + u000);
            else {
                float tt = g ? ((m <= 383) ? rn[(m*3+2)*2+1] : 0.f)
                             : (rn[(m*3+2)*2+0] + un[(m*3+2)*2+0]);
                v = r000 + u001 - Cs[1] + Cs[m] + tt;
            }
            rawv[k] = v;
        }
    }
    __syncthreads();
    // ---- block logsumexp of rawv; p0 in place ----
    {
        float lmax = -3.0e38f;
        for (int k = tid; k < 769; k += 256) lmax = fmaxf(lmax, rawv[k]);
        #pragma unroll
        for (int d = 1; d < 64; d <<= 1) lmax = fmaxf(lmax, __shfl_xor(lmax, d));
        if (lane == 0) red[wvid] = lmax;
    }
    __syncthreads();
    {
        float gmax = fmaxf(fmaxf(red[0], red[1]), fmaxf(red[2], red[3]));
        float lsum = 0.f;
        for (int k = tid; k < 769; k += 256) lsum += __expf(rawv[k] - gmax);
        #pragma unroll
        for (int d = 1; d < 64; d <<= 1) lsum += __shfl_xor(lsum, d);
        if (lane == 0) red[4 + wvid] = lsum;
        __syncthreads();
        float lse = gmax + __logf(red[4] + red[5] + red[6] + red[7]);
        for (int k = tid; k < 769; k += 256) rawv[k] = __expf(rawv[k] - lse);
    }
    __syncthreads();
    // ---- per-lane regs ((j,j+3) pairing), esl build, n-ballot — all pre-TAB ----
    const int j0 = lane*6;
    const int lane12 = lane*12;
    v2f CemA=mkv2(cAEM[j0],cAEM[j0+3]), CemB=mkv2(cAEM[j0+1],cAEM[j0+4]), CemC=mkv2(cAEM[j0+2],cAEM[j0+5]);
    v2f CeiA=mkv2(cAEI[j0],cAEI[j0+3]), CeiB=mkv2(cAEI[j0+1],cAEI[j0+4]), CeiC=mkv2(cAEI[j0+2],cAEI[j0+5]);
    v2f CdmaA=mkv2(cDMA[j0],cDMA[j0+3]), CdmaB=mkv2(cDMA[j0+1],cDMA[j0+4]), CdmaC=mkv2(cDMA[j0+2],cDMA[j0+5]);
    v2f CdmbA=mkv2(cDMB[j0],cDMB[j0+3]), CdmbB=mkv2(cDMB[j0+1],cDMB[j0+4]), CdmbC=mkv2(cDMB[j0+2],cDMB[j0+5]);
    v2f CdiaA=mkv2(cDIA[j0],cDIA[j0+3]), CdiaB=mkv2(cDIA[j0+1],cDIA[j0+4]), CdiaC=mkv2(cDIA[j0+2],cDIA[j0+5]);
    v2f CdibA=mkv2(cDIB[j0],cDIB[j0+3]), CdibB=mkv2(cDIB[j0+1],cDIB[j0+4]), CdibC=mkv2(cDIB[j0+2],cDIB[j0+5]);
    v2f CgmA=mkv2(etmm[j0],etmm[j0+3]), CgmB=mkv2(etmm[j0+1],etmm[j0+4]), CgmC=mkv2(etmm[j0+2],etmm[j0+5]);
    v2f CgiA=mkv2(etii[j0],etii[j0+3]), CgiB=mkv2(etii[j0+1],etii[j0+4]), CgiC=mkv2(etii[j0+2],etii[j0+5]);
    v2f PmA=mkv2(rawv[j0],rawv[j0+3]), PmB=mkv2(rawv[j0+1],rawv[j0+4]), PmC=mkv2(rawv[j0+2],rawv[j0+5]);
    v2f PiA=mkv2(rawv[384+j0],rawv[384+j0+3]), PiB=mkv2(rawv[384+j0+1],rawv[384+j0+4]), PiC=mkv2(rawv[384+j0+2],rawv[384+j0+5]);
    float pi384 = rawv[768];
    const float W0=ews[j0], w1=ews[j0+1], w2=ews[j0+2], w3=ews[j0+3], w4=ews[j0+4], w5=ews[j0+5];
    {   // esl[t] = es-bits (low byte cleared) | clamped letter
        int l = (int)lets[tid]; l = (l > 20) ? 20 : l;
        union { float f; int i; } u; u.f = sES[l];
        ((int*)smem)[L_ESL + tid] = (u.i & 0xffffff00) | l;
    }
    int n = 0;
    #pragma unroll
    for (int c = 0; c < 4; ++c)
        n += __popcll(__ballot(lets[c*64 + lane] != (unsigned char)21));
    __syncthreads();
    // ---- emission table build (overwrites all setup scratch) ----
    // record per lane: [mA.x mA.y mB.x mB.y mC.x mC.y | iA.x iA.y iB.x iB.y iC.x iC.y]
    for (int row = tid; row < 768; row += 256) {
        const float* src = (row < 384) ? (ps + row*21) : (iseq + (row-384)*21);
        float mx = -3.0e38f;
        for (int a = 0; a < 21; ++a) mx = fmaxf(mx, src[a]);
        float sm2 = 0.f;
        for (int a = 0; a < 21; ++a) sm2 += __expf(src[a]-mx);
        float inv = 1.0f / sm2;
        int j = (row < 384) ? row : (row - 384);
        int k = j % 6;
        int slot = (j/6)*12 + ((row < 384) ? 0 : 6) + (k%3)*2 + (k/3);
        float* dst = smem + L_TAB + slot;
        for (int a = 0; a < 21; ++a) dst[a*768] = __expf(src[a]-mx)*inv;
    }
    __syncthreads();
    if (wvid != 0) return;

    // ================= wave 0: the sequential scan =================
    const int* iesl = ((const int*)smem) + L_ESL;

    const float pw1 = W0, pw2 = pw1*w1, pw3 = pw2*w2, pw4 = pw3*w3, pw5 = pw4*w4;
    const float W = pw5*w5;
    float p_ = W;
    const float Ar0 = p_;
    const float Ar0s = wsr1(Ar0);
    { float q = __shfl_up(p_, 1); p_ *= q; } const float Ar1 = p_;
    { float q = __shfl_up(p_, 2); p_ *= q; } const float Ar2 = p_;
    { float q = __shfl_up(p_, 4); p_ *= q; } const float Ar3 = p_;
    float prefR = W;
    #pragma unroll
    for (int d = 1; d < 16; d <<= 1) { float q = __shfl_up(prefR, d); if ((lane & 15) >= d) prefR *= q; }
    const int rw = lane >> 4;
    const float A15 = (rw == 1 || rw == 3) ? prefR : 0.f;
    const float s47 = __shfl(prefR, 47);
    const float A31 = (rw == 2) ? prefR : ((rw == 3) ? prefR * s47 : 0.f);
    bool bad = (Ar1 != 0.f) || (Ar2 != 0.f) || (Ar3 != 0.f)
             || ((A15 != 0.f) && ((lane & 15) >= 1))
             || ((A31 != 0.f) && (lane >= 33));
    const bool fastAll = (__ballot(bad) == 0ull);

    int ksum = 0;
    {   // t = 0 emission + exponent renorm (letter valid; n >= 1)
        int e0 = iesl[0];
        int lm0 = e0 & 0xff;
        const float* bp = smem + lm0*768 + lane12;
        float4 q0 = ((const float4*)bp)[0], q1 = ((const float4*)bp)[1], q2 = ((const float4*)bp)[2];
        PmA *= mkv2(q0.x,q0.y); PmB *= mkv2(q0.z,q0.w); PmC *= mkv2(q1.x,q1.y);
        PiA *= mkv2(q1.z,q1.w); PiB *= mkv2(q2.x,q2.y); PiC *= mkv2(q2.z,q2.w);
        union { int i; float f; } u0; u0.i = e0 & 0xffffff00;
        pi384 *= u0.f;
        RENORM;
    }

    // 4-buffer rotating pipeline, prefetch distance 3
    Buf b0, b1, b2, b3;
    { int e = iesl[1]; FILLE(b1, e); }
    { int e = iesl[2]; FILLE(b2, e); }
    { int e = iesl[3]; FILLE(b3, e); }
    int eU = iesl[4];

    const int total = n - 1;           // steps t = 1 .. n-1 (t >= n are exact no-ops)
    const int bodies = total / 12;
    const int rem = total - bodies*12;
    int t = 1;
    if (fastAll) SCANLOOP(1);
    else         SCANLOOP(0);

    v2f sv = PmA + PmB + PmC + PiA + PiB + PiC;
    float s = sv.x + sv.y + ((lane == 63) ? pi384 : 0.f);
    s += fdpp<0x111>(s); s += fdpp<0x112>(s); s += fdpp<0x114>(s); s += fdpp<0x118>(s);
    s += fdpp<0x142>(s); s += fdpp<0x143>(s);
    if (lane == 63) out[b] = lsc[0] * (__logf(s) - (float)ksum * 0.69314718055994531f);
}

extern "C" void kernel_launch(void* const* d_in, const int* in_sizes, int n_in,
                              void* d_out, int out_size, void* d_ws, size_t ws_size,
                              hipStream_t stream)
{
    const float* ps   = (const float*)d_in[0];  // precursor_seq (384,21)
    const float* iseq = (const float*)d_in[1];  // insert_seq (385,21)
    const float* ins  = (const float*)d_in[2];  // insert (384,3,2)
    const float* del  = (const float*)d_in[3];  // delete (384,3,2)
    const float* seq  = (const float*)d_in[4];  // seq_data (64,256,21)
    const float* lsc  = (const float*)d_in[5];  // local_scale (1,)
    float* out = (float*)d_out;
    hmm_fused<<<64, 256, 0, stream>>>(ps, iseq, ins, del, seq, lsc, out);
}